// Round 1
// baseline (3526.885 us; speedup 1.0000x reference)
//
#include <hip/hip_runtime.h>
#include <math.h>

#define N_NODES  30000
#define N_EDGES  240000
#define E_TOT    270000   // N_EDGES + N_NODES self loops
#define N_GRAPHS 300

// ---------------------------------------------------------------------------
// helpers
// ---------------------------------------------------------------------------
__device__ inline void atomicMaxF(float* addr, float val) {
    // ordered-int trick: works for all finite floats and +-inf (no NaNs here)
    if (val >= 0.f) atomicMax((int*)addr, __float_as_int(val));
    else            atomicMin((unsigned int*)addr, __float_as_uint(val));
}

__global__ void fill_kernel(float* __restrict__ p, float v, int n) {
    int i = blockIdx.x * blockDim.x + threadIdx.x;
    if (i < n) p[i] = v;
}

// ---------------------------------------------------------------------------
// node-level GEMM: out[n, co] = act( sum_ci h[n,ci]*W[ci,co] + b[co] )
// act: 0 = none, 1 = bn + relu
// one block handles NT nodes x COUT cols; W read amortized over NT nodes
// ---------------------------------------------------------------------------
template<int CIN, int COUT, int NT>
__global__ void node_gemm(const float* __restrict__ h, const float* __restrict__ W,
                          const float* __restrict__ bias, float* __restrict__ out,
                          const float* __restrict__ bnp, int n_nodes, int act) {
    __shared__ float sh[NT][CIN];
    const int n0 = blockIdx.x * NT;
    const int t  = threadIdx.x;            // 0..COUT-1
    for (int i = t; i < NT * CIN; i += COUT) {
        int nn = i / CIN, ci = i - nn * CIN;
        int n = n0 + nn;
        sh[nn][ci] = (n < n_nodes) ? h[(size_t)n * CIN + ci] : 0.f;
    }
    __syncthreads();
    float acc[NT];
#pragma unroll
    for (int j = 0; j < NT; ++j) acc[j] = bias[t];
    for (int ci = 0; ci < CIN; ++ci) {
        float w = W[ci * COUT + t];        // coalesced across t
#pragma unroll
        for (int j = 0; j < NT; ++j) acc[j] += sh[j][ci] * w;
    }
#pragma unroll
    for (int j = 0; j < NT; ++j) {
        int n = n0 + j;
        if (n >= n_nodes) break;
        float v = acc[j];
        if (act == 1) {
            float g = bnp[t], be = bnp[COUT + t], m = bnp[2 * COUT + t], va = bnp[3 * COUT + t];
            v = g * (v - m) * rsqrtf(va + 1e-5f) + be;
            v = fmaxf(v, 0.f);
        }
        out[(size_t)n * COUT + t] = v;
    }
}

// ---------------------------------------------------------------------------
// per-edge logit: logit[e,h] = sum_c leaky_relu(xl[src,h,c]+xr[dst,h,c]) * att[h,c]
// one wave (64 lanes) per edge; lane covers HC/64 consecutive channels
// also atomic segment-max into lmax[dst,h]
// ---------------------------------------------------------------------------
template<int H, int C>
__global__ void edge_logit(const float* __restrict__ xl, const float* __restrict__ xr,
                           const int* __restrict__ ei, const float* __restrict__ att,
                           float* __restrict__ elog, float* __restrict__ lmax) {
    constexpr int HC = H * C;
    constexpr int PER = HC / 64;
    constexpr int GROUP = 64 / H;          // lanes per head
    int gid  = blockIdx.x * blockDim.x + threadIdx.x;
    int e    = gid >> 6;
    int lane = gid & 63;
    if (e >= E_TOT) return;
    int s, d;
    if (e < N_EDGES) { s = ei[e]; d = ei[N_EDGES + e]; }
    else             { s = e - N_EDGES; d = s; }
    const float* xls = xl + (size_t)s * HC + lane * PER;
    const float* xrd = xr + (size_t)d * HC + lane * PER;
    float p = 0.f;
#pragma unroll
    for (int k = 0; k < PER; ++k) {
        float v = xls[k] + xrd[k];
        v = (v > 0.f) ? v : 0.2f * v;
        p += v * att[lane * PER + k];
    }
#pragma unroll
    for (int off = GROUP / 2; off; off >>= 1) p += __shfl_xor(p, off, 64);
    if ((lane & (GROUP - 1)) == 0) {
        int hh = lane / GROUP;
        elog[(size_t)e * H + hh] = p;
        atomicMaxF(&lmax[d * H + hh], p);
    }
}

// ---------------------------------------------------------------------------
// ex = exp(logit - lmax[dst,h]); den[dst,h] += ex  (in-place overwrite logit)
// ---------------------------------------------------------------------------
template<int H>
__global__ void edge_exp(float* __restrict__ elog, const float* __restrict__ lmax,
                         float* __restrict__ den, const int* __restrict__ ei) {
    int idx = blockIdx.x * blockDim.x + threadIdx.x;
    if (idx >= E_TOT * H) return;
    int e  = idx / H;
    int hh = idx - e * H;
    int d  = (e < N_EDGES) ? ei[N_EDGES + e] : e - N_EDGES;
    float ex = expf(elog[idx] - lmax[d * H + hh]);
    elog[idx] = ex;
    atomicAdd(&den[d * H + hh], ex);
}

// ---------------------------------------------------------------------------
// out[dst,h,c] += (ex/(den[dst,h]+1e-16)) * xl[src,h,c]; one wave per edge
// ---------------------------------------------------------------------------
template<int H, int C>
__global__ void edge_aggr(const float* __restrict__ xl, const float* __restrict__ elog,
                          const float* __restrict__ den, const int* __restrict__ ei,
                          float* __restrict__ out) {
    constexpr int HC = H * C;
    constexpr int PER = HC / 64;
    constexpr int GROUP = 64 / H;
    int gid  = blockIdx.x * blockDim.x + threadIdx.x;
    int e    = gid >> 6;
    int lane = gid & 63;
    if (e >= E_TOT) return;
    int s, d;
    if (e < N_EDGES) { s = ei[e]; d = ei[N_EDGES + e]; }
    else             { s = e - N_EDGES; d = s; }
    int hh = lane / GROUP;
    float alpha = elog[(size_t)e * H + hh] / (den[d * H + hh] + 1e-16f);
    const float* xls = xl + (size_t)s * HC + lane * PER;
    float* od = out + (size_t)d * HC + lane * PER;
#pragma unroll
    for (int k = 0; k < PER; ++k) atomicAdd(&od[k], alpha * xls[k]);
}

// ---------------------------------------------------------------------------
// x[n,j] = elu( bn( x[n,j] + bias[j] ) )   in-place; Cfull is power of two
// ---------------------------------------------------------------------------
__global__ void bias_bn_elu(float* __restrict__ x, const float* __restrict__ bias,
                            const float* __restrict__ bnp, int total, int Cfull, int cmask) {
    int idx = blockIdx.x * blockDim.x + threadIdx.x;
    if (idx >= total) return;
    int j = idx & cmask;
    float v = x[idx] + bias[j];
    float g = bnp[j], be = bnp[Cfull + j], m = bnp[2 * Cfull + j], va = bnp[3 * Cfull + j];
    v = g * (v - m) * rsqrtf(va + 1e-5f) + be;
    x[idx] = (v > 0.f) ? v : (expf(v) - 1.f);
}

// ---------------------------------------------------------------------------
// graph pooling accumulate: per (node, c) with C=128
// ---------------------------------------------------------------------------
__global__ void pool_accum(const float* __restrict__ h, const int* __restrict__ batch,
                           float* __restrict__ psum, float* __restrict__ pmax,
                           float* __restrict__ pcnt) {
    int idx = blockIdx.x * blockDim.x + threadIdx.x;
    if (idx >= N_NODES * 128) return;
    int node = idx >> 7;
    int c    = idx & 127;
    int b = batch[node];
    float v = h[idx];
    atomicAdd(&psum[b * 128 + c], v);
    atomicMaxF(&pmax[b * 128 + c], v);
    if (c == 0) atomicAdd(&pcnt[b], 1.f);
}

__global__ void pool_fin(const float* __restrict__ psum, const float* __restrict__ pmax,
                         const float* __restrict__ pcnt, float* __restrict__ g) {
    int idx = blockIdx.x * blockDim.x + threadIdx.x;
    if (idx >= N_GRAPHS * 128) return;
    int b = idx >> 7;
    int c = idx & 127;
    float cnt = fmaxf(pcnt[b], 1.f);
    g[b * 256 + c] = psum[idx] / cnt;
    float m = pmax[idx];
    g[b * 256 + 128 + c] = isfinite(m) ? m : 0.f;
}

// ---------------------------------------------------------------------------
// classifier head: one block (128 threads) per graph
// z1 = relu(bn(g@w1+b1)); z2 = relu(z1@w2+b2); out = log_softmax(z2@w3+b3)
// ---------------------------------------------------------------------------
__global__ void classifier(const float* __restrict__ g,
                           const float* __restrict__ w1, const float* __restrict__ b1,
                           const float* __restrict__ bnp,
                           const float* __restrict__ w2, const float* __restrict__ b2,
                           const float* __restrict__ w3, const float* __restrict__ b3,
                           float* __restrict__ out) {
    __shared__ float sg[256];
    __shared__ float sz1[128];
    __shared__ float sz2[64];
    __shared__ float sz3[2];
    int b = blockIdx.x, t = threadIdx.x;
    sg[t]       = g[b * 256 + t];
    sg[128 + t] = g[b * 256 + 128 + t];
    __syncthreads();
    float acc = b1[t];
    for (int i = 0; i < 256; ++i) acc += sg[i] * w1[i * 128 + t];
    float ga = bnp[t], be = bnp[128 + t], m = bnp[256 + t], va = bnp[384 + t];
    acc = ga * (acc - m) * rsqrtf(va + 1e-5f) + be;
    sz1[t] = fmaxf(acc, 0.f);
    __syncthreads();
    if (t < 64) {
        float a2 = b2[t];
        for (int i = 0; i < 128; ++i) a2 += sz1[i] * w2[i * 64 + t];
        sz2[t] = fmaxf(a2, 0.f);
    }
    __syncthreads();
    if (t < 2) {
        float a3 = b3[t];
        for (int i = 0; i < 64; ++i) a3 += sz2[i] * w3[i * 2 + t];
        sz3[t] = a3;
    }
    __syncthreads();
    if (t < 2) {
        float mm = fmaxf(sz3[0], sz3[1]);
        float lse = mm + logf(expf(sz3[0] - mm) + expf(sz3[1] - mm));
        out[b * 2 + t] = sz3[t] - lse;
    }
}

// ---------------------------------------------------------------------------
// launch
// ---------------------------------------------------------------------------
static inline int cdiv(int a, int b) { return (a + b - 1) / b; }

extern "C" void kernel_launch(void* const* d_in, const int* in_sizes, int n_in,
                              void* d_out, int out_size, void* d_ws, size_t ws_size,
                              hipStream_t stream) {
    const float* x       = (const float*)d_in[0];
    const int*   ei      = (const int*)d_in[1];
    const int*   batch   = (const int*)d_in[2];
    const float* w_in    = (const float*)d_in[3];
    const float* b_in    = (const float*)d_in[4];
    const float* bn_in   = (const float*)d_in[5];
    const float* g1_wl   = (const float*)d_in[6];
    const float* g1_bl   = (const float*)d_in[7];
    const float* g1_wr   = (const float*)d_in[8];
    const float* g1_br   = (const float*)d_in[9];
    const float* g1_att  = (const float*)d_in[10];
    const float* g1_bias = (const float*)d_in[11];
    const float* bn1     = (const float*)d_in[12];
    const float* g2_wl   = (const float*)d_in[13];
    const float* g2_bl   = (const float*)d_in[14];
    const float* g2_wr   = (const float*)d_in[15];
    const float* g2_br   = (const float*)d_in[16];
    const float* g2_att  = (const float*)d_in[17];
    const float* g2_bias = (const float*)d_in[18];
    const float* bn2     = (const float*)d_in[19];
    const float* g3_wl   = (const float*)d_in[20];
    const float* g3_bl   = (const float*)d_in[21];
    const float* g3_wr   = (const float*)d_in[22];
    const float* g3_br   = (const float*)d_in[23];
    const float* g3_att  = (const float*)d_in[24];
    const float* g3_bias = (const float*)d_in[25];
    const float* bn3     = (const float*)d_in[26];
    const float* c_w1    = (const float*)d_in[27];
    const float* c_b1    = (const float*)d_in[28];
    const float* c_bn    = (const float*)d_in[29];
    const float* c_w2    = (const float*)d_in[30];
    const float* c_b2    = (const float*)d_in[31];
    const float* c_w3    = (const float*)d_in[32];
    const float* c_b3    = (const float*)d_in[33];
    float* out = (float*)d_out;

    // workspace layout (floats)
    float* ws = (float*)d_ws;
    const size_t NHC = (size_t)N_NODES * 256;       // 7,680,000
    float* bufA = ws;                               // h buffers (ping-pong)
    float* bufB = ws + NHC;
    float* bufC = ws + 2 * NHC;
    float* bufD = ws + 3 * NHC;
    float* elog = ws + 4 * NHC;                     // E_TOT * 4
    float* lmax = elog + (size_t)E_TOT * 4;         // N * 4
    float* den  = lmax + (size_t)N_NODES * 4;       // N * 4
    float* psum = den + (size_t)N_NODES * 4;        // 300*128
    float* pmax = psum + N_GRAPHS * 128;
    float* pcnt = pmax + N_GRAPHS * 128;            // 300
    float* gbuf = pcnt + N_GRAPHS;                  // 300*256

    const int BT = 256;
    const int edge_blocks = cdiv(E_TOT * 64, BT);   // wave per edge

    // ---- input layer: h0 = relu(bn(x @ w_in + b_in))  -> bufA (N x 64)
    node_gemm<5, 64, 4><<<cdiv(N_NODES, 4), 64, 0, stream>>>(x, w_in, b_in, bufA, bn_in, N_NODES, 1);

    // ---- GAT layer 1: 64 -> 4x64, in bufA, out bufD
    node_gemm<64, 256, 4><<<cdiv(N_NODES, 4), 256, 0, stream>>>(bufA, g1_wl, g1_bl, bufB, nullptr, N_NODES, 0);
    node_gemm<64, 256, 4><<<cdiv(N_NODES, 4), 256, 0, stream>>>(bufA, g1_wr, g1_br, bufC, nullptr, N_NODES, 0);
    fill_kernel<<<cdiv(N_NODES * 4, BT), BT, 0, stream>>>(lmax, -INFINITY, N_NODES * 4);
    fill_kernel<<<cdiv(N_NODES * 4, BT), BT, 0, stream>>>(den, 0.f, N_NODES * 4);
    fill_kernel<<<cdiv((int)NHC, BT), BT, 0, stream>>>(bufD, 0.f, (int)NHC);
    edge_logit<4, 64><<<edge_blocks, BT, 0, stream>>>(bufB, bufC, ei, g1_att, elog, lmax);
    edge_exp<4><<<cdiv(E_TOT * 4, BT), BT, 0, stream>>>(elog, lmax, den, ei);
    edge_aggr<4, 64><<<edge_blocks, BT, 0, stream>>>(bufB, elog, den, ei, bufD);
    bias_bn_elu<<<cdiv((int)NHC, BT), BT, 0, stream>>>(bufD, g1_bias, bn1, (int)NHC, 256, 255);

    // ---- GAT layer 2: 256 -> 4x64, in bufD, out bufA
    node_gemm<256, 256, 4><<<cdiv(N_NODES, 4), 256, 0, stream>>>(bufD, g2_wl, g2_bl, bufB, nullptr, N_NODES, 0);
    node_gemm<256, 256, 4><<<cdiv(N_NODES, 4), 256, 0, stream>>>(bufD, g2_wr, g2_br, bufC, nullptr, N_NODES, 0);
    fill_kernel<<<cdiv(N_NODES * 4, BT), BT, 0, stream>>>(lmax, -INFINITY, N_NODES * 4);
    fill_kernel<<<cdiv(N_NODES * 4, BT), BT, 0, stream>>>(den, 0.f, N_NODES * 4);
    fill_kernel<<<cdiv((int)NHC, BT), BT, 0, stream>>>(bufA, 0.f, (int)NHC);
    edge_logit<4, 64><<<edge_blocks, BT, 0, stream>>>(bufB, bufC, ei, g2_att, elog, lmax);
    edge_exp<4><<<cdiv(E_TOT * 4, BT), BT, 0, stream>>>(elog, lmax, den, ei);
    edge_aggr<4, 64><<<edge_blocks, BT, 0, stream>>>(bufB, elog, den, ei, bufA);
    bias_bn_elu<<<cdiv((int)NHC, BT), BT, 0, stream>>>(bufA, g2_bias, bn2, (int)NHC, 256, 255);

    // ---- GAT layer 3: 256 -> 1x128, in bufA, out bufD (N x 128)
    const int NH3 = N_NODES * 128;
    node_gemm<256, 128, 4><<<cdiv(N_NODES, 4), 128, 0, stream>>>(bufA, g3_wl, g3_bl, bufB, nullptr, N_NODES, 0);
    node_gemm<256, 128, 4><<<cdiv(N_NODES, 4), 128, 0, stream>>>(bufA, g3_wr, g3_br, bufC, nullptr, N_NODES, 0);
    fill_kernel<<<cdiv(N_NODES, BT), BT, 0, stream>>>(lmax, -INFINITY, N_NODES);
    fill_kernel<<<cdiv(N_NODES, BT), BT, 0, stream>>>(den, 0.f, N_NODES);
    fill_kernel<<<cdiv(NH3, BT), BT, 0, stream>>>(bufD, 0.f, NH3);
    edge_logit<1, 128><<<edge_blocks, BT, 0, stream>>>(bufB, bufC, ei, g3_att, elog, lmax);
    edge_exp<1><<<cdiv(E_TOT, BT), BT, 0, stream>>>(elog, lmax, den, ei);
    edge_aggr<1, 128><<<edge_blocks, BT, 0, stream>>>(bufB, elog, den, ei, bufD);
    bias_bn_elu<<<cdiv(NH3, BT), BT, 0, stream>>>(bufD, g3_bias, bn3, NH3, 128, 127);

    // ---- pooling: mean + max per graph -> gbuf (300 x 256)
    fill_kernel<<<cdiv(N_GRAPHS * 128, BT), BT, 0, stream>>>(psum, 0.f, N_GRAPHS * 128);
    fill_kernel<<<cdiv(N_GRAPHS * 128, BT), BT, 0, stream>>>(pmax, -INFINITY, N_GRAPHS * 128);
    fill_kernel<<<cdiv(N_GRAPHS, BT), BT, 0, stream>>>(pcnt, 0.f, N_GRAPHS);
    pool_accum<<<cdiv(NH3, BT), BT, 0, stream>>>(bufD, batch, psum, pmax, pcnt);
    pool_fin<<<cdiv(N_GRAPHS * 128, BT), BT, 0, stream>>>(psum, pmax, pcnt, gbuf);

    // ---- classifier head
    classifier<<<N_GRAPHS, 128, 0, stream>>>(gbuf, c_w1, c_b1, c_bn, c_w2, c_b2, c_w3, c_b3, out);
}

// Round 2
// 1479.907 us; speedup vs baseline: 2.3832x; 2.3832x over previous
//
#include <hip/hip_runtime.h>
#include <math.h>

#define N_NODES  30000
#define N_EDGES  240000
#define E_TOT    270000   // N_EDGES + N_NODES self loops
#define N_GRAPHS 300

// ---------------------------------------------------------------------------
// small utility kernels
// ---------------------------------------------------------------------------
__global__ void ifill(int* __restrict__ p, int v, int n) {
    int i = blockIdx.x * blockDim.x + threadIdx.x;
    if (i < n) p[i] = v;
}

// ---------------------------------------------------------------------------
// CSR build: histogram -> two-level exclusive scan -> scatter
// ---------------------------------------------------------------------------
__global__ void hist_edges(const int* __restrict__ ei, int* __restrict__ deg) {
    int e = blockIdx.x * blockDim.x + threadIdx.x;
    if (e >= E_TOT) return;
    int d = (e < N_EDGES) ? ei[N_EDGES + e] : e - N_EDGES;
    atomicAdd(&deg[d], 1);
}

__global__ void hist_batch(const int* __restrict__ batch, int* __restrict__ gdeg) {
    int i = blockIdx.x * blockDim.x + threadIdx.x;
    if (i < N_NODES) atomicAdd(&gdeg[batch[i]], 1);
}

// per-block exclusive scan of 256-chunks; writes block sums
__global__ void scan_partial(const int* __restrict__ in, int* __restrict__ local,
                             int* __restrict__ bsums, int n) {
    __shared__ int s[256];
    int t = threadIdx.x;
    int gid = blockIdx.x * 256 + t;
    int v = (gid < n) ? in[gid] : 0;
    s[t] = v;
    __syncthreads();
    for (int off = 1; off < 256; off <<= 1) {
        int u = (t >= off) ? s[t - off] : 0;
        __syncthreads();
        s[t] += u;
        __syncthreads();
    }
    if (gid < n) local[gid] = s[t] - v;           // exclusive
    if (t == 255) bsums[blockIdx.x] = s[255];
}

// single-block exclusive scan of block sums (nb <= 128)
__global__ void scan_tops(int* __restrict__ bsums, int nb) {
    __shared__ int s[128];
    int t = threadIdx.x;
    int v = (t < nb) ? bsums[t] : 0;
    s[t] = v;
    __syncthreads();
    for (int off = 1; off < 128; off <<= 1) {
        int u = (t >= off) ? s[t - off] : 0;
        __syncthreads();
        s[t] += u;
        __syncthreads();
    }
    if (t < nb) bsums[t] = s[t] - v;              // exclusive offsets
}

__global__ void scan_add(const int* __restrict__ local, const int* __restrict__ bsums,
                         int* __restrict__ out, int n, int total) {
    int gid = blockIdx.x * blockDim.x + threadIdx.x;
    if (gid < n) out[gid] = local[gid] + bsums[gid >> 8];
    if (gid == 0) out[n] = total;
}

__global__ void csr_scatter(const int* __restrict__ ei, const int* __restrict__ row_start,
                            int* __restrict__ cnt, int* __restrict__ esrc) {
    int e = blockIdx.x * blockDim.x + threadIdx.x;
    if (e >= E_TOT) return;
    int s, d;
    if (e < N_EDGES) { s = ei[e]; d = ei[N_EDGES + e]; }
    else             { s = e - N_EDGES; d = s; }
    int slot = row_start[d] + atomicAdd(&cnt[d], 1);
    esrc[slot] = s;
}

// ---------------------------------------------------------------------------
// node-level GEMM: out[n, co] = act( sum_ci h[n,ci]*W[ci,co] + b[co] )
// act: 0 = none, 1 = bn + relu
// ---------------------------------------------------------------------------
template<int CIN, int COUT, int NT>
__global__ void node_gemm(const float* __restrict__ h, const float* __restrict__ W,
                          const float* __restrict__ bias, float* __restrict__ out,
                          const float* __restrict__ bnp, int n_nodes, int act) {
    __shared__ float sh[NT][CIN];
    const int n0 = blockIdx.x * NT;
    const int t  = threadIdx.x;            // 0..COUT-1
    for (int i = t; i < NT * CIN; i += COUT) {
        int nn = i / CIN, ci = i - nn * CIN;
        int n = n0 + nn;
        sh[nn][ci] = (n < n_nodes) ? h[(size_t)n * CIN + ci] : 0.f;
    }
    __syncthreads();
    float acc[NT];
#pragma unroll
    for (int j = 0; j < NT; ++j) acc[j] = bias[t];
    for (int ci = 0; ci < CIN; ++ci) {
        float w = W[ci * COUT + t];        // coalesced across t
#pragma unroll
        for (int j = 0; j < NT; ++j) acc[j] += sh[j][ci] * w;
    }
#pragma unroll
    for (int j = 0; j < NT; ++j) {
        int n = n0 + j;
        if (n >= n_nodes) break;
        float v = acc[j];
        if (act == 1) {
            float g = bnp[t], be = bnp[COUT + t], m = bnp[2 * COUT + t], va = bnp[3 * COUT + t];
            v = g * (v - m) * rsqrtf(va + 1e-5f) + be;
            v = fmaxf(v, 0.f);
        }
        out[(size_t)n * COUT + t] = v;
    }
}

// ---------------------------------------------------------------------------
// fused GATv2 gather: one wave per (node, head), online softmax over incoming
// edges, weighted sum of xl[src], then bias + bn + elu epilogue. No atomics.
// ---------------------------------------------------------------------------
template<int H, int C>
__global__ void gat_gather(const float* __restrict__ xl, const float* __restrict__ xr,
                           const int* __restrict__ row_start, const int* __restrict__ esrc,
                           const float* __restrict__ att, const float* __restrict__ gbias,
                           const float* __restrict__ bnp, float* __restrict__ out) {
    constexpr int HC  = H * C;
    constexpr int PER = C / 64;            // channels per lane
    int wid  = (blockIdx.x * blockDim.x + threadIdx.x) >> 6;
    int lane = threadIdx.x & 63;
    if (wid >= N_NODES * H) return;
    int node = wid / H;
    int h    = wid - node * H;
    const int base = h * C + lane * PER;

    float rr[PER], av[PER], acc[PER];
#pragma unroll
    for (int k = 0; k < PER; ++k) {
        rr[k]  = xr[(size_t)node * HC + base + k];
        av[k]  = att[base + k];            // att is [H, C] flat == base indexing
        acc[k] = 0.f;
    }
    float m = -INFINITY, l = 0.f;
    int j0 = row_start[node], j1 = row_start[node + 1];
    for (int j = j0; j < j1; ++j) {
        int s = esrc[j];
        float xls[PER];
        float p = 0.f;
#pragma unroll
        for (int k = 0; k < PER; ++k) {
            xls[k] = xl[(size_t)s * HC + base + k];
            float v = xls[k] + rr[k];
            v = (v > 0.f) ? v : 0.2f * v;  // leaky_relu 0.2
            p += v * av[k];
        }
#pragma unroll
        for (int off = 32; off; off >>= 1) p += __shfl_xor(p, off, 64);
        float mn    = fmaxf(m, p);
        float scale = expf(m - mn);        // first iter: expf(-inf)=0
        float w     = expf(p - mn);
        l = l * scale + w;
#pragma unroll
        for (int k = 0; k < PER; ++k) acc[k] = acc[k] * scale + w * xls[k];
        m = mn;
    }
    float inv = 1.f / (l + 1e-16f);
#pragma unroll
    for (int k = 0; k < PER; ++k) {
        float v = acc[k] * inv + gbias[base + k];
        float g  = bnp[base + k], be = bnp[HC + base + k];
        float mm = bnp[2 * HC + base + k], va = bnp[3 * HC + base + k];
        v = g * (v - mm) * rsqrtf(va + 1e-5f) + be;
        out[(size_t)node * HC + base + k] = (v > 0.f) ? v : (expf(v) - 1.f);
    }
}

// ---------------------------------------------------------------------------
// per-graph pooling (batch is sorted -> contiguous node ranges), no atomics
// ---------------------------------------------------------------------------
__global__ void pool_graph(const float* __restrict__ h, const int* __restrict__ gstart,
                           float* __restrict__ gbuf) {
    int g = blockIdx.x;
    int t = threadIdx.x;                   // 0..127
    int a = gstart[g], b = gstart[g + 1];
    float sum = 0.f, mx = -INFINITY;
    for (int i = a; i < b; ++i) {
        float v = h[(size_t)i * 128 + t];
        sum += v;
        mx = fmaxf(mx, v);
    }
    float cnt = fmaxf((float)(b - a), 1.f);
    gbuf[g * 256 + t]       = sum / cnt;
    gbuf[g * 256 + 128 + t] = (b > a) ? mx : 0.f;
}

// ---------------------------------------------------------------------------
// classifier head: one block (128 threads) per graph
// ---------------------------------------------------------------------------
__global__ void classifier(const float* __restrict__ g,
                           const float* __restrict__ w1, const float* __restrict__ b1,
                           const float* __restrict__ bnp,
                           const float* __restrict__ w2, const float* __restrict__ b2,
                           const float* __restrict__ w3, const float* __restrict__ b3,
                           float* __restrict__ out) {
    __shared__ float sg[256];
    __shared__ float sz1[128];
    __shared__ float sz2[64];
    __shared__ float sz3[2];
    int b = blockIdx.x, t = threadIdx.x;
    sg[t]       = g[b * 256 + t];
    sg[128 + t] = g[b * 256 + 128 + t];
    __syncthreads();
    float acc = b1[t];
    for (int i = 0; i < 256; ++i) acc += sg[i] * w1[i * 128 + t];
    float ga = bnp[t], be = bnp[128 + t], m = bnp[256 + t], va = bnp[384 + t];
    acc = ga * (acc - m) * rsqrtf(va + 1e-5f) + be;
    sz1[t] = fmaxf(acc, 0.f);
    __syncthreads();
    if (t < 64) {
        float a2 = b2[t];
        for (int i = 0; i < 128; ++i) a2 += sz1[i] * w2[i * 64 + t];
        sz2[t] = fmaxf(a2, 0.f);
    }
    __syncthreads();
    if (t < 2) {
        float a3 = b3[t];
        for (int i = 0; i < 64; ++i) a3 += sz2[i] * w3[i * 2 + t];
        sz3[t] = a3;
    }
    __syncthreads();
    if (t < 2) {
        float mm = fmaxf(sz3[0], sz3[1]);
        float lse = mm + logf(expf(sz3[0] - mm) + expf(sz3[1] - mm));
        out[b * 2 + t] = sz3[t] - lse;
    }
}

// ---------------------------------------------------------------------------
// launch
// ---------------------------------------------------------------------------
static inline int cdiv(int a, int b) { return (a + b - 1) / b; }

extern "C" void kernel_launch(void* const* d_in, const int* in_sizes, int n_in,
                              void* d_out, int out_size, void* d_ws, size_t ws_size,
                              hipStream_t stream) {
    const float* x       = (const float*)d_in[0];
    const int*   ei      = (const int*)d_in[1];
    const int*   batch   = (const int*)d_in[2];
    const float* w_in    = (const float*)d_in[3];
    const float* b_in    = (const float*)d_in[4];
    const float* bn_in   = (const float*)d_in[5];
    const float* g1_wl   = (const float*)d_in[6];
    const float* g1_bl   = (const float*)d_in[7];
    const float* g1_wr   = (const float*)d_in[8];
    const float* g1_br   = (const float*)d_in[9];
    const float* g1_att  = (const float*)d_in[10];
    const float* g1_bias = (const float*)d_in[11];
    const float* bn1     = (const float*)d_in[12];
    const float* g2_wl   = (const float*)d_in[13];
    const float* g2_bl   = (const float*)d_in[14];
    const float* g2_wr   = (const float*)d_in[15];
    const float* g2_br   = (const float*)d_in[16];
    const float* g2_att  = (const float*)d_in[17];
    const float* g2_bias = (const float*)d_in[18];
    const float* bn2     = (const float*)d_in[19];
    const float* g3_wl   = (const float*)d_in[20];
    const float* g3_bl   = (const float*)d_in[21];
    const float* g3_wr   = (const float*)d_in[22];
    const float* g3_br   = (const float*)d_in[23];
    const float* g3_att  = (const float*)d_in[24];
    const float* g3_bias = (const float*)d_in[25];
    const float* bn3     = (const float*)d_in[26];
    const float* c_w1    = (const float*)d_in[27];
    const float* c_b1    = (const float*)d_in[28];
    const float* c_bn    = (const float*)d_in[29];
    const float* c_w2    = (const float*)d_in[30];
    const float* c_b2    = (const float*)d_in[31];
    const float* c_w3    = (const float*)d_in[32];
    const float* c_b3    = (const float*)d_in[33];
    float* out = (float*)d_out;

    // ---- workspace layout
    float* ws = (float*)d_ws;
    const size_t NHC = (size_t)N_NODES * 256;       // 7,680,000
    float* bufA = ws;                               // node feature buffers
    float* bufB = ws + NHC;
    float* bufC = ws + 2 * NHC;
    float* bufD = ws + 3 * NHC;
    float* gbuf = ws + 4 * NHC;                     // 300*256
    int*   iw   = (int*)(ws + 4 * NHC + N_GRAPHS * 256);
    int* deg       = iw;                            // 30000
    int* cnt       = iw + 30000;                    // 30000 (scatter cursors)
    int* slocal    = iw + 60000;                    // 30000 (scan scratch)
    int* bsums     = iw + 90000;                    // 128
    int* row_start = iw + 90128;                    // 30001
    int* esrc      = iw + 120129;                   // 270000
    int* gdeg      = iw + 390129;                   // 300
    int* glocal    = iw + 390429;                   // 300
    int* gbsums    = iw + 390729;                   // 8
    int* gstart    = iw + 390737;                   // 301

    const int BT = 256;

    // ---- CSR build by destination (same graph for all 3 layers)
    ifill<<<cdiv(60000, BT), BT, 0, stream>>>(deg, 0, 60000);        // deg + cnt
    ifill<<<cdiv(300, BT), BT, 0, stream>>>(gdeg, 0, 300);
    hist_edges<<<cdiv(E_TOT, BT), BT, 0, stream>>>(ei, deg);
    hist_batch<<<cdiv(N_NODES, BT), BT, 0, stream>>>(batch, gdeg);
    // edge scan: n=30000 -> 118 blocks
    scan_partial<<<cdiv(N_NODES, 256), 256, 0, stream>>>(deg, slocal, bsums, N_NODES);
    scan_tops<<<1, 128, 0, stream>>>(bsums, cdiv(N_NODES, 256));
    scan_add<<<cdiv(N_NODES, BT), BT, 0, stream>>>(slocal, bsums, row_start, N_NODES, E_TOT);
    csr_scatter<<<cdiv(E_TOT, BT), BT, 0, stream>>>(ei, row_start, cnt, esrc);
    // graph-start scan: n=300 -> 2 blocks
    scan_partial<<<cdiv(N_GRAPHS, 256), 256, 0, stream>>>(gdeg, glocal, gbsums, N_GRAPHS);
    scan_tops<<<1, 128, 0, stream>>>(gbsums, cdiv(N_GRAPHS, 256));
    scan_add<<<cdiv(N_GRAPHS, BT), BT, 0, stream>>>(glocal, gbsums, gstart, N_GRAPHS, N_NODES);

    // ---- input layer: h0 = relu(bn(x @ w_in + b_in))  -> bufA (N x 64)
    node_gemm<5, 64, 4><<<cdiv(N_NODES, 4), 64, 0, stream>>>(x, w_in, b_in, bufA, bn_in, N_NODES, 1);

    // ---- GAT layer 1: 64 -> 4x64, in bufA, out bufD (fused aggr+bias+bn+elu)
    node_gemm<64, 256, 4><<<cdiv(N_NODES, 4), 256, 0, stream>>>(bufA, g1_wl, g1_bl, bufB, nullptr, N_NODES, 0);
    node_gemm<64, 256, 4><<<cdiv(N_NODES, 4), 256, 0, stream>>>(bufA, g1_wr, g1_br, bufC, nullptr, N_NODES, 0);
    gat_gather<4, 64><<<cdiv(N_NODES * 4 * 64, BT), BT, 0, stream>>>(bufB, bufC, row_start, esrc, g1_att, g1_bias, bn1, bufD);

    // ---- GAT layer 2: 256 -> 4x64, in bufD, out bufA
    node_gemm<256, 256, 4><<<cdiv(N_NODES, 4), 256, 0, stream>>>(bufD, g2_wl, g2_bl, bufB, nullptr, N_NODES, 0);
    node_gemm<256, 256, 4><<<cdiv(N_NODES, 4), 256, 0, stream>>>(bufD, g2_wr, g2_br, bufC, nullptr, N_NODES, 0);
    gat_gather<4, 64><<<cdiv(N_NODES * 4 * 64, BT), BT, 0, stream>>>(bufB, bufC, row_start, esrc, g2_att, g2_bias, bn2, bufA);

    // ---- GAT layer 3: 256 -> 1x128, in bufA, out bufD (N x 128)
    node_gemm<256, 128, 4><<<cdiv(N_NODES, 4), 128, 0, stream>>>(bufA, g3_wl, g3_bl, bufB, nullptr, N_NODES, 0);
    node_gemm<256, 128, 4><<<cdiv(N_NODES, 4), 128, 0, stream>>>(bufA, g3_wr, g3_br, bufC, nullptr, N_NODES, 0);
    gat_gather<1, 128><<<cdiv(N_NODES * 64, BT), BT, 0, stream>>>(bufB, bufC, row_start, esrc, g3_att, g3_bias, bn3, bufD);

    // ---- pooling: mean + max per graph -> gbuf (300 x 256), contiguous ranges
    pool_graph<<<N_GRAPHS, 128, 0, stream>>>(bufD, gstart, gbuf);

    // ---- classifier head
    classifier<<<N_GRAPHS, 128, 0, stream>>>(gbuf, c_w1, c_b1, c_bn, c_w2, c_b2, c_w3, c_b3, out);
}

// Round 3
// 814.895 us; speedup vs baseline: 4.3280x; 1.8161x over previous
//
#include <hip/hip_runtime.h>
#include <math.h>

#define N_NODES  30000
#define N_EDGES  240000
#define E_TOT    270000   // N_EDGES + N_NODES self loops
#define N_GRAPHS 300

// ---------------------------------------------------------------------------
// small utility kernels
// ---------------------------------------------------------------------------
__global__ void ifill(int* __restrict__ p, int v, int n) {
    int i = blockIdx.x * blockDim.x + threadIdx.x;
    if (i < n) p[i] = v;
}

// ---------------------------------------------------------------------------
// CSR build: histogram -> two-level exclusive scan -> scatter
// ---------------------------------------------------------------------------
__global__ void hist_edges(const int* __restrict__ ei, int* __restrict__ deg) {
    int e = blockIdx.x * blockDim.x + threadIdx.x;
    if (e >= E_TOT) return;
    int d = (e < N_EDGES) ? ei[N_EDGES + e] : e - N_EDGES;
    atomicAdd(&deg[d], 1);
}

__global__ void hist_batch(const int* __restrict__ batch, int* __restrict__ gdeg) {
    int i = blockIdx.x * blockDim.x + threadIdx.x;
    if (i < N_NODES) atomicAdd(&gdeg[batch[i]], 1);
}

// per-block exclusive scan of 256-chunks; writes block sums
__global__ void scan_partial(const int* __restrict__ in, int* __restrict__ local,
                             int* __restrict__ bsums, int n) {
    __shared__ int s[256];
    int t = threadIdx.x;
    int gid = blockIdx.x * 256 + t;
    int v = (gid < n) ? in[gid] : 0;
    s[t] = v;
    __syncthreads();
    for (int off = 1; off < 256; off <<= 1) {
        int u = (t >= off) ? s[t - off] : 0;
        __syncthreads();
        s[t] += u;
        __syncthreads();
    }
    if (gid < n) local[gid] = s[t] - v;           // exclusive
    if (t == 255) bsums[blockIdx.x] = s[255];
}

// single-block exclusive scan of block sums (nb <= 128)
__global__ void scan_tops(int* __restrict__ bsums, int nb) {
    __shared__ int s[128];
    int t = threadIdx.x;
    int v = (t < nb) ? bsums[t] : 0;
    s[t] = v;
    __syncthreads();
    for (int off = 1; off < 128; off <<= 1) {
        int u = (t >= off) ? s[t - off] : 0;
        __syncthreads();
        s[t] += u;
        __syncthreads();
    }
    if (t < nb) bsums[t] = s[t] - v;              // exclusive offsets
}

__global__ void scan_add(const int* __restrict__ local, const int* __restrict__ bsums,
                         int* __restrict__ out, int n, int total) {
    int gid = blockIdx.x * blockDim.x + threadIdx.x;
    if (gid < n) out[gid] = local[gid] + bsums[gid >> 8];
    if (gid == 0) out[n] = total;
}

__global__ void csr_scatter(const int* __restrict__ ei, const int* __restrict__ row_start,
                            int* __restrict__ cnt, int* __restrict__ esrc) {
    int e = blockIdx.x * blockDim.x + threadIdx.x;
    if (e >= E_TOT) return;
    int s, d;
    if (e < N_EDGES) { s = ei[e]; d = ei[N_EDGES + e]; }
    else             { s = e - N_EDGES; d = s; }
    int slot = row_start[d] + atomicAdd(&cnt[d], 1);
    esrc[slot] = s;
}

// ---------------------------------------------------------------------------
// register-tiled GEMM: out[n, co] = A[n,:] @ W[:,co] + bias[co]
// BM=128 x BN=128 tile, BK=32, 256 threads, 8x8 outputs/thread.
// 64 FMA per 4 ds_read_b128 (16:1) vs old kernel's 1:1 -> LDS pipe relieved.
// ---------------------------------------------------------------------------
template<int K, int COUT>
__global__ __launch_bounds__(256, 2)
void gemm_tiled(const float* __restrict__ A, const float* __restrict__ W,
                const float* __restrict__ bias, float* __restrict__ out, int N) {
    constexpr int BM = 128, BN = 128, BK = 32;
    __shared__ float As[BK][BM + 4];   // stride 132: float4-aligned, softens transpose-write conflicts
    __shared__ float Bs[BK][BN];
    const int tid = threadIdx.x;
    const int tx = tid & 15;           // col group 0..15
    const int ty = tid >> 4;           // row group 0..15
    const int n0   = blockIdx.x * BM;
    const int col0 = blockIdx.y * BN;

    float acc[8][8];
#pragma unroll
    for (int r = 0; r < 8; ++r)
#pragma unroll
        for (int c = 0; c < 8; ++c) acc[r][c] = 0.f;

    const int a_node = tid >> 3;          // 0..31
    const int a_k    = (tid & 7) * 4;     // 0,4,..,28
    const int b_k    = tid >> 5;          // 0..7
    const int b_c    = (tid & 31) * 4;    // 0..124

    for (int kt = 0; kt < K; kt += BK) {
        // ---- stage A tile (transposed into As[k][node])
#pragma unroll
        for (int r = 0; r < 4; ++r) {
            int node = r * 32 + a_node;
            int gn = n0 + node;
            float4 v = {0.f, 0.f, 0.f, 0.f};
            if (gn < N) v = *(const float4*)(A + (size_t)gn * K + kt + a_k);
            As[a_k + 0][node] = v.x;
            As[a_k + 1][node] = v.y;
            As[a_k + 2][node] = v.z;
            As[a_k + 3][node] = v.w;
        }
        // ---- stage B tile (no transpose)
#pragma unroll
        for (int r = 0; r < 4; ++r) {
            int k = r * 8 + b_k;
            float4 v = *(const float4*)(W + (size_t)(kt + k) * COUT + col0 + b_c);
            *(float4*)(&Bs[k][b_c]) = v;
        }
        __syncthreads();
        // ---- inner product: split tiles so b128 reads are lane-consecutive
#pragma unroll 4
        for (int k = 0; k < BK; ++k) {
            float a[8], b[8];
            *(float4*)(a)     = *(const float4*)(&As[k][ty * 4]);
            *(float4*)(a + 4) = *(const float4*)(&As[k][64 + ty * 4]);
            *(float4*)(b)     = *(const float4*)(&Bs[k][tx * 4]);
            *(float4*)(b + 4) = *(const float4*)(&Bs[k][64 + tx * 4]);
#pragma unroll
            for (int r = 0; r < 8; ++r)
#pragma unroll
                for (int c = 0; c < 8; ++c) acc[r][c] += a[r] * b[c];
        }
        __syncthreads();
    }
    // ---- epilogue: + bias, coalesced float4 stores
#pragma unroll
    for (int rr = 0; rr < 2; ++rr)
#pragma unroll
        for (int r = 0; r < 4; ++r) {
            int row = n0 + rr * 64 + ty * 4 + r;
            if (row >= N) continue;
#pragma unroll
            for (int cc = 0; cc < 2; ++cc) {
                int col = col0 + cc * 64 + tx * 4;
                float4 v;
                v.x = acc[rr * 4 + r][cc * 4 + 0] + bias[col + 0];
                v.y = acc[rr * 4 + r][cc * 4 + 1] + bias[col + 1];
                v.z = acc[rr * 4 + r][cc * 4 + 2] + bias[col + 2];
                v.w = acc[rr * 4 + r][cc * 4 + 3] + bias[col + 3];
                *(float4*)(out + (size_t)row * COUT + col) = v;
            }
        }
}

// ---------------------------------------------------------------------------
// input layer GEMM (tiny K=5): old scheme is fine here
// ---------------------------------------------------------------------------
template<int CIN, int COUT, int NT>
__global__ void node_gemm(const float* __restrict__ h, const float* __restrict__ W,
                          const float* __restrict__ bias, float* __restrict__ out,
                          const float* __restrict__ bnp, int n_nodes, int act) {
    __shared__ float sh[NT][CIN];
    const int n0 = blockIdx.x * NT;
    const int t  = threadIdx.x;
    for (int i = t; i < NT * CIN; i += COUT) {
        int nn = i / CIN, ci = i - nn * CIN;
        int n = n0 + nn;
        sh[nn][ci] = (n < n_nodes) ? h[(size_t)n * CIN + ci] : 0.f;
    }
    __syncthreads();
    float acc[NT];
#pragma unroll
    for (int j = 0; j < NT; ++j) acc[j] = bias[t];
    for (int ci = 0; ci < CIN; ++ci) {
        float w = W[ci * COUT + t];
#pragma unroll
        for (int j = 0; j < NT; ++j) acc[j] += sh[j][ci] * w;
    }
#pragma unroll
    for (int j = 0; j < NT; ++j) {
        int n = n0 + j;
        if (n >= n_nodes) break;
        float v = acc[j];
        if (act == 1) {
            float g = bnp[t], be = bnp[COUT + t], m = bnp[2 * COUT + t], va = bnp[3 * COUT + t];
            v = g * (v - m) * rsqrtf(va + 1e-5f) + be;
            v = fmaxf(v, 0.f);
        }
        out[(size_t)n * COUT + t] = v;
    }
}

// ---------------------------------------------------------------------------
// fused GATv2 gather: one wave per (node, head), online softmax over incoming
// edges, weighted sum of xl[src], then bias + bn + elu epilogue. No atomics.
// ---------------------------------------------------------------------------
template<int H, int C>
__global__ void gat_gather(const float* __restrict__ xl, const float* __restrict__ xr,
                           const int* __restrict__ row_start, const int* __restrict__ esrc,
                           const float* __restrict__ att, const float* __restrict__ gbias,
                           const float* __restrict__ bnp, float* __restrict__ out) {
    constexpr int HC  = H * C;
    constexpr int PER = C / 64;            // channels per lane
    int wid  = (blockIdx.x * blockDim.x + threadIdx.x) >> 6;
    int lane = threadIdx.x & 63;
    if (wid >= N_NODES * H) return;
    int node = wid / H;
    int h    = wid - node * H;
    const int base = h * C + lane * PER;

    float rr[PER], av[PER], acc[PER];
#pragma unroll
    for (int k = 0; k < PER; ++k) {
        rr[k]  = xr[(size_t)node * HC + base + k];
        av[k]  = att[base + k];
        acc[k] = 0.f;
    }
    float m = -INFINITY, l = 0.f;
    int j0 = row_start[node], j1 = row_start[node + 1];
    for (int j = j0; j < j1; ++j) {
        int s = esrc[j];
        float xls[PER];
        float p = 0.f;
#pragma unroll
        for (int k = 0; k < PER; ++k) {
            xls[k] = xl[(size_t)s * HC + base + k];
            float v = xls[k] + rr[k];
            v = (v > 0.f) ? v : 0.2f * v;  // leaky_relu 0.2
            p += v * av[k];
        }
#pragma unroll
        for (int off = 32; off; off >>= 1) p += __shfl_xor(p, off, 64);
        float mn    = fmaxf(m, p);
        float scale = expf(m - mn);        // first iter: expf(-inf)=0
        float w     = expf(p - mn);
        l = l * scale + w;
#pragma unroll
        for (int k = 0; k < PER; ++k) acc[k] = acc[k] * scale + w * xls[k];
        m = mn;
    }
    float inv = 1.f / (l + 1e-16f);
#pragma unroll
    for (int k = 0; k < PER; ++k) {
        float v = acc[k] * inv + gbias[base + k];
        float g  = bnp[base + k], be = bnp[HC + base + k];
        float mm = bnp[2 * HC + base + k], va = bnp[3 * HC + base + k];
        v = g * (v - mm) * rsqrtf(va + 1e-5f) + be;
        out[(size_t)node * HC + base + k] = (v > 0.f) ? v : (expf(v) - 1.f);
    }
}

// ---------------------------------------------------------------------------
// per-graph pooling (batch is sorted -> contiguous node ranges), no atomics
// ---------------------------------------------------------------------------
__global__ void pool_graph(const float* __restrict__ h, const int* __restrict__ gstart,
                           float* __restrict__ gbuf) {
    int g = blockIdx.x;
    int t = threadIdx.x;                   // 0..127
    int a = gstart[g], b = gstart[g + 1];
    float sum = 0.f, mx = -INFINITY;
    for (int i = a; i < b; ++i) {
        float v = h[(size_t)i * 128 + t];
        sum += v;
        mx = fmaxf(mx, v);
    }
    float cnt = fmaxf((float)(b - a), 1.f);
    gbuf[g * 256 + t]       = sum / cnt;
    gbuf[g * 256 + 128 + t] = (b > a) ? mx : 0.f;
}

// ---------------------------------------------------------------------------
// classifier head: one block (128 threads) per graph
// ---------------------------------------------------------------------------
__global__ void classifier(const float* __restrict__ g,
                           const float* __restrict__ w1, const float* __restrict__ b1,
                           const float* __restrict__ bnp,
                           const float* __restrict__ w2, const float* __restrict__ b2,
                           const float* __restrict__ w3, const float* __restrict__ b3,
                           float* __restrict__ out) {
    __shared__ float sg[256];
    __shared__ float sz1[128];
    __shared__ float sz2[64];
    __shared__ float sz3[2];
    int b = blockIdx.x, t = threadIdx.x;
    sg[t]       = g[b * 256 + t];
    sg[128 + t] = g[b * 256 + 128 + t];
    __syncthreads();
    float acc = b1[t];
    for (int i = 0; i < 256; ++i) acc += sg[i] * w1[i * 128 + t];
    float ga = bnp[t], be = bnp[128 + t], m = bnp[256 + t], va = bnp[384 + t];
    acc = ga * (acc - m) * rsqrtf(va + 1e-5f) + be;
    sz1[t] = fmaxf(acc, 0.f);
    __syncthreads();
    if (t < 64) {
        float a2 = b2[t];
        for (int i = 0; i < 128; ++i) a2 += sz1[i] * w2[i * 64 + t];
        sz2[t] = fmaxf(a2, 0.f);
    }
    __syncthreads();
    if (t < 2) {
        float a3 = b3[t];
        for (int i = 0; i < 64; ++i) a3 += sz2[i] * w3[i * 2 + t];
        sz3[t] = a3;
    }
    __syncthreads();
    if (t < 2) {
        float mm = fmaxf(sz3[0], sz3[1]);
        float lse = mm + logf(expf(sz3[0] - mm) + expf(sz3[1] - mm));
        out[b * 2 + t] = sz3[t] - lse;
    }
}

// ---------------------------------------------------------------------------
// launch
// ---------------------------------------------------------------------------
static inline int cdiv(int a, int b) { return (a + b - 1) / b; }

extern "C" void kernel_launch(void* const* d_in, const int* in_sizes, int n_in,
                              void* d_out, int out_size, void* d_ws, size_t ws_size,
                              hipStream_t stream) {
    const float* x       = (const float*)d_in[0];
    const int*   ei      = (const int*)d_in[1];
    const int*   batch   = (const int*)d_in[2];
    const float* w_in    = (const float*)d_in[3];
    const float* b_in    = (const float*)d_in[4];
    const float* bn_in   = (const float*)d_in[5];
    const float* g1_wl   = (const float*)d_in[6];
    const float* g1_bl   = (const float*)d_in[7];
    const float* g1_wr   = (const float*)d_in[8];
    const float* g1_br   = (const float*)d_in[9];
    const float* g1_att  = (const float*)d_in[10];
    const float* g1_bias = (const float*)d_in[11];
    const float* bn1     = (const float*)d_in[12];
    const float* g2_wl   = (const float*)d_in[13];
    const float* g2_bl   = (const float*)d_in[14];
    const float* g2_wr   = (const float*)d_in[15];
    const float* g2_br   = (const float*)d_in[16];
    const float* g2_att  = (const float*)d_in[17];
    const float* g2_bias = (const float*)d_in[18];
    const float* bn2     = (const float*)d_in[19];
    const float* g3_wl   = (const float*)d_in[20];
    const float* g3_bl   = (const float*)d_in[21];
    const float* g3_wr   = (const float*)d_in[22];
    const float* g3_br   = (const float*)d_in[23];
    const float* g3_att  = (const float*)d_in[24];
    const float* g3_bias = (const float*)d_in[25];
    const float* bn3     = (const float*)d_in[26];
    const float* c_w1    = (const float*)d_in[27];
    const float* c_b1    = (const float*)d_in[28];
    const float* c_bn    = (const float*)d_in[29];
    const float* c_w2    = (const float*)d_in[30];
    const float* c_b2    = (const float*)d_in[31];
    const float* c_w3    = (const float*)d_in[32];
    const float* c_b3    = (const float*)d_in[33];
    float* out = (float*)d_out;

    // ---- workspace layout
    float* ws = (float*)d_ws;
    const size_t NHC = (size_t)N_NODES * 256;       // 7,680,000
    float* bufA = ws;                               // node feature buffers
    float* bufB = ws + NHC;
    float* bufC = ws + 2 * NHC;
    float* bufD = ws + 3 * NHC;
    float* gbuf = ws + 4 * NHC;                     // 300*256
    int*   iw   = (int*)(ws + 4 * NHC + N_GRAPHS * 256);
    int* deg       = iw;                            // 30000
    int* cnt       = iw + 30000;                    // 30000 (scatter cursors)
    int* slocal    = iw + 60000;                    // 30000 (scan scratch)
    int* bsums     = iw + 90000;                    // 128
    int* row_start = iw + 90128;                    // 30001
    int* esrc      = iw + 120129;                   // 270000
    int* gdeg      = iw + 390129;                   // 300
    int* glocal    = iw + 390429;                   // 300
    int* gbsums    = iw + 390729;                   // 8
    int* gstart    = iw + 390737;                   // 301

    const int BT = 256;
    const int NTILES = cdiv(N_NODES, 128);          // 235

    // ---- CSR build by destination (same graph for all 3 layers)
    ifill<<<cdiv(60000, BT), BT, 0, stream>>>(deg, 0, 60000);        // deg + cnt
    ifill<<<cdiv(300, BT), BT, 0, stream>>>(gdeg, 0, 300);
    hist_edges<<<cdiv(E_TOT, BT), BT, 0, stream>>>(ei, deg);
    hist_batch<<<cdiv(N_NODES, BT), BT, 0, stream>>>(batch, gdeg);
    scan_partial<<<cdiv(N_NODES, 256), 256, 0, stream>>>(deg, slocal, bsums, N_NODES);
    scan_tops<<<1, 128, 0, stream>>>(bsums, cdiv(N_NODES, 256));
    scan_add<<<cdiv(N_NODES, BT), BT, 0, stream>>>(slocal, bsums, row_start, N_NODES, E_TOT);
    csr_scatter<<<cdiv(E_TOT, BT), BT, 0, stream>>>(ei, row_start, cnt, esrc);
    scan_partial<<<cdiv(N_GRAPHS, 256), 256, 0, stream>>>(gdeg, glocal, gbsums, N_GRAPHS);
    scan_tops<<<1, 128, 0, stream>>>(gbsums, cdiv(N_GRAPHS, 256));
    scan_add<<<cdiv(N_GRAPHS, BT), BT, 0, stream>>>(glocal, gbsums, gstart, N_GRAPHS, N_NODES);

    // ---- input layer: h0 = relu(bn(x @ w_in + b_in))  -> bufA (N x 64)
    node_gemm<5, 64, 4><<<cdiv(N_NODES, 4), 64, 0, stream>>>(x, w_in, b_in, bufA, bn_in, N_NODES, 1);

    // ---- GAT layer 1: 64 -> 4x64, in bufA, out bufD (fused aggr+bias+bn+elu)
    gemm_tiled<64, 256><<<dim3(NTILES, 2), 256, 0, stream>>>(bufA, g1_wl, g1_bl, bufB, N_NODES);
    gemm_tiled<64, 256><<<dim3(NTILES, 2), 256, 0, stream>>>(bufA, g1_wr, g1_br, bufC, N_NODES);
    gat_gather<4, 64><<<cdiv(N_NODES * 4 * 64, BT), BT, 0, stream>>>(bufB, bufC, row_start, esrc, g1_att, g1_bias, bn1, bufD);

    // ---- GAT layer 2: 256 -> 4x64, in bufD, out bufA
    gemm_tiled<256, 256><<<dim3(NTILES, 2), 256, 0, stream>>>(bufD, g2_wl, g2_bl, bufB, N_NODES);
    gemm_tiled<256, 256><<<dim3(NTILES, 2), 256, 0, stream>>>(bufD, g2_wr, g2_br, bufC, N_NODES);
    gat_gather<4, 64><<<cdiv(N_NODES * 4 * 64, BT), BT, 0, stream>>>(bufB, bufC, row_start, esrc, g2_att, g2_bias, bn2, bufA);

    // ---- GAT layer 3: 256 -> 1x128, in bufA, out bufD (N x 128)
    gemm_tiled<256, 128><<<dim3(NTILES, 1), 256, 0, stream>>>(bufA, g3_wl, g3_bl, bufB, N_NODES);
    gemm_tiled<256, 128><<<dim3(NTILES, 1), 256, 0, stream>>>(bufA, g3_wr, g3_br, bufC, N_NODES);
    gat_gather<1, 128><<<cdiv(N_NODES * 64, BT), BT, 0, stream>>>(bufB, bufC, row_start, esrc, g3_att, g3_bias, bn3, bufD);

    // ---- pooling: mean + max per graph -> gbuf (300 x 256), contiguous ranges
    pool_graph<<<N_GRAPHS, 128, 0, stream>>>(bufD, gstart, gbuf);

    // ---- classifier head
    classifier<<<N_GRAPHS, 128, 0, stream>>>(gbuf, c_w1, c_b1, c_bn, c_w2, c_b2, c_w3, c_b3, out);
}

// Round 4
// 630.172 us; speedup vs baseline: 5.5967x; 1.2931x over previous
//
#include <hip/hip_runtime.h>
#include <math.h>

#define N_NODES  30000
#define N_EDGES  240000
#define E_TOT    270000   // N_EDGES + N_NODES self loops
#define N_GRAPHS 300

// ---------------------------------------------------------------------------
// small utility kernels
// ---------------------------------------------------------------------------
__global__ void ifill(int* __restrict__ p, int v, int n) {
    int i = blockIdx.x * blockDim.x + threadIdx.x;
    if (i < n) p[i] = v;
}

// ---------------------------------------------------------------------------
// CSR build: histogram -> two-level exclusive scan -> scatter
// ---------------------------------------------------------------------------
__global__ void hist_edges(const int* __restrict__ ei, int* __restrict__ deg) {
    int e = blockIdx.x * blockDim.x + threadIdx.x;
    if (e >= E_TOT) return;
    int d = (e < N_EDGES) ? ei[N_EDGES + e] : e - N_EDGES;
    atomicAdd(&deg[d], 1);
}

__global__ void hist_batch(const int* __restrict__ batch, int* __restrict__ gdeg) {
    int i = blockIdx.x * blockDim.x + threadIdx.x;
    if (i < N_NODES) atomicAdd(&gdeg[batch[i]], 1);
}

// per-block exclusive scan of 256-chunks; writes block sums
__global__ void scan_partial(const int* __restrict__ in, int* __restrict__ local,
                             int* __restrict__ bsums, int n) {
    __shared__ int s[256];
    int t = threadIdx.x;
    int gid = blockIdx.x * 256 + t;
    int v = (gid < n) ? in[gid] : 0;
    s[t] = v;
    __syncthreads();
    for (int off = 1; off < 256; off <<= 1) {
        int u = (t >= off) ? s[t - off] : 0;
        __syncthreads();
        s[t] += u;
        __syncthreads();
    }
    if (gid < n) local[gid] = s[t] - v;           // exclusive
    if (t == 255) bsums[blockIdx.x] = s[255];
}

// single-block exclusive scan of block sums (nb <= 128)
__global__ void scan_tops(int* __restrict__ bsums, int nb) {
    __shared__ int s[128];
    int t = threadIdx.x;
    int v = (t < nb) ? bsums[t] : 0;
    s[t] = v;
    __syncthreads();
    for (int off = 1; off < 128; off <<= 1) {
        int u = (t >= off) ? s[t - off] : 0;
        __syncthreads();
        s[t] += u;
        __syncthreads();
    }
    if (t < nb) bsums[t] = s[t] - v;              // exclusive offsets
}

__global__ void scan_add(const int* __restrict__ local, const int* __restrict__ bsums,
                         int* __restrict__ out, int n, int total) {
    int gid = blockIdx.x * blockDim.x + threadIdx.x;
    if (gid < n) out[gid] = local[gid] + bsums[gid >> 8];
    if (gid == 0) out[n] = total;
}

__global__ void csr_scatter(const int* __restrict__ ei, const int* __restrict__ row_start,
                            int* __restrict__ cnt, int* __restrict__ esrc) {
    int e = blockIdx.x * blockDim.x + threadIdx.x;
    if (e >= E_TOT) return;
    int s, d;
    if (e < N_EDGES) { s = ei[e]; d = ei[N_EDGES + e]; }
    else             { s = e - N_EDGES; d = s; }
    int slot = row_start[d] + atomicAdd(&cnt[d], 1);
    esrc[slot] = s;
}

// ---------------------------------------------------------------------------
// register-tiled GEMM: out[n, co] = A[n,:] @ W[:,co] + bias[co]
// BM=128 x BN=128 tile, BK=32, 256 threads, 8x8 outputs/thread.
// ---------------------------------------------------------------------------
template<int K, int COUT>
__global__ __launch_bounds__(256, 2)
void gemm_tiled(const float* __restrict__ A, const float* __restrict__ W,
                const float* __restrict__ bias, float* __restrict__ out, int N) {
    constexpr int BM = 128, BN = 128, BK = 32;
    __shared__ float As[BK][BM + 4];
    __shared__ float Bs[BK][BN];
    const int tid = threadIdx.x;
    const int tx = tid & 15;
    const int ty = tid >> 4;
    const int n0   = blockIdx.x * BM;
    const int col0 = blockIdx.y * BN;

    float acc[8][8];
#pragma unroll
    for (int r = 0; r < 8; ++r)
#pragma unroll
        for (int c = 0; c < 8; ++c) acc[r][c] = 0.f;

    const int a_node = tid >> 3;
    const int a_k    = (tid & 7) * 4;
    const int b_k    = tid >> 5;
    const int b_c    = (tid & 31) * 4;

    for (int kt = 0; kt < K; kt += BK) {
#pragma unroll
        for (int r = 0; r < 4; ++r) {
            int node = r * 32 + a_node;
            int gn = n0 + node;
            float4 v = {0.f, 0.f, 0.f, 0.f};
            if (gn < N) v = *(const float4*)(A + (size_t)gn * K + kt + a_k);
            As[a_k + 0][node] = v.x;
            As[a_k + 1][node] = v.y;
            As[a_k + 2][node] = v.z;
            As[a_k + 3][node] = v.w;
        }
#pragma unroll
        for (int r = 0; r < 4; ++r) {
            int k = r * 8 + b_k;
            float4 v = *(const float4*)(W + (size_t)(kt + k) * COUT + col0 + b_c);
            *(float4*)(&Bs[k][b_c]) = v;
        }
        __syncthreads();
#pragma unroll 4
        for (int k = 0; k < BK; ++k) {
            float a[8], b[8];
            *(float4*)(a)     = *(const float4*)(&As[k][ty * 4]);
            *(float4*)(a + 4) = *(const float4*)(&As[k][64 + ty * 4]);
            *(float4*)(b)     = *(const float4*)(&Bs[k][tx * 4]);
            *(float4*)(b + 4) = *(const float4*)(&Bs[k][64 + tx * 4]);
#pragma unroll
            for (int r = 0; r < 8; ++r)
#pragma unroll
                for (int c = 0; c < 8; ++c) acc[r][c] += a[r] * b[c];
        }
        __syncthreads();
    }
#pragma unroll
    for (int rr = 0; rr < 2; ++rr)
#pragma unroll
        for (int r = 0; r < 4; ++r) {
            int row = n0 + rr * 64 + ty * 4 + r;
            if (row >= N) continue;
#pragma unroll
            for (int cc = 0; cc < 2; ++cc) {
                int col = col0 + cc * 64 + tx * 4;
                float4 v;
                v.x = acc[rr * 4 + r][cc * 4 + 0] + bias[col + 0];
                v.y = acc[rr * 4 + r][cc * 4 + 1] + bias[col + 1];
                v.z = acc[rr * 4 + r][cc * 4 + 2] + bias[col + 2];
                v.w = acc[rr * 4 + r][cc * 4 + 3] + bias[col + 3];
                *(float4*)(out + (size_t)row * COUT + col) = v;
            }
        }
}

// ---------------------------------------------------------------------------
// input layer GEMM (tiny K=5)
// ---------------------------------------------------------------------------
template<int CIN, int COUT, int NT>
__global__ void node_gemm(const float* __restrict__ h, const float* __restrict__ W,
                          const float* __restrict__ bias, float* __restrict__ out,
                          const float* __restrict__ bnp, int n_nodes, int act) {
    __shared__ float sh[NT][CIN];
    const int n0 = blockIdx.x * NT;
    const int t  = threadIdx.x;
    for (int i = t; i < NT * CIN; i += COUT) {
        int nn = i / CIN, ci = i - nn * CIN;
        int n = n0 + nn;
        sh[nn][ci] = (n < n_nodes) ? h[(size_t)n * CIN + ci] : 0.f;
    }
    __syncthreads();
    float acc[NT];
#pragma unroll
    for (int j = 0; j < NT; ++j) acc[j] = bias[t];
    for (int ci = 0; ci < CIN; ++ci) {
        float w = W[ci * COUT + t];
#pragma unroll
        for (int j = 0; j < NT; ++j) acc[j] += sh[j][ci] * w;
    }
#pragma unroll
    for (int j = 0; j < NT; ++j) {
        int n = n0 + j;
        if (n >= n_nodes) break;
        float v = acc[j];
        if (act == 1) {
            float g = bnp[t], be = bnp[COUT + t], m = bnp[2 * COUT + t], va = bnp[3 * COUT + t];
            v = g * (v - m) * rsqrtf(va + 1e-5f) + be;
            v = fmaxf(v, 0.f);
        }
        out[(size_t)n * COUT + t] = v;
    }
}

// ---------------------------------------------------------------------------
// fused GATv2 gather: ONE WAVE PER NODE covering all H heads (HC channels).
// Lane l holds channels [l*PER, l*PER+PER); head = lane/GROUP. Online softmax
// per head (per-lane SIMT: one v_exp serves all heads). Edge indices are
// prefetched coalesced and broadcast via shuffle. Epilogue: bias+bn+elu.
// ---------------------------------------------------------------------------
template<int H, int C>
__global__ __launch_bounds__(256)
void gat_gather(const float* __restrict__ xl, const float* __restrict__ xr,
                const int* __restrict__ row_start, const int* __restrict__ esrc,
                const float* __restrict__ att, const float* __restrict__ gbias,
                const float* __restrict__ bnp, float* __restrict__ out) {
    constexpr int HC    = H * C;
    constexpr int PER   = HC / 64;         // channels per lane (4 or 2)
    constexpr int GROUP = 64 / H;          // lanes per head (16 or 64)
    int node = (blockIdx.x * blockDim.x + threadIdx.x) >> 6;
    int lane = threadIdx.x & 63;
    if (node >= N_NODES) return;
    const int base = lane * PER;

    float rr[PER], av[PER], acc[PER];
    if constexpr (PER == 4) {
        *(float4*)rr = *(const float4*)(xr + (size_t)node * HC + base);
        *(float4*)av = *(const float4*)(att + base);
    } else {
        *(float2*)rr = *(const float2*)(xr + (size_t)node * HC + base);
        *(float2*)av = *(const float2*)(att + base);
    }
#pragma unroll
    for (int k = 0; k < PER; ++k) acc[k] = 0.f;

    float m = -INFINITY, l = 0.f;
    const int j0 = row_start[node], j1 = row_start[node + 1];
    for (int jc = j0; jc < j1; jc += 64) {
        int nedge = min(64, j1 - jc);
        int ev = (jc + lane < j1) ? esrc[jc + lane] : 0;   // coalesced prefetch
        for (int jj = 0; jj < nedge; ++jj) {
            int s = __shfl(ev, jj, 64);                    // broadcast edge src
            float xls[PER];
            if constexpr (PER == 4)
                *(float4*)xls = *(const float4*)(xl + (size_t)s * HC + base);
            else
                *(float2*)xls = *(const float2*)(xl + (size_t)s * HC + base);
            float p = 0.f;
#pragma unroll
            for (int k = 0; k < PER; ++k) {
                float v = xls[k] + rr[k];
                v = (v > 0.f) ? v : 0.2f * v;              // leaky_relu 0.2
                p = fmaf(v, av[k], p);
            }
#pragma unroll
            for (int off = GROUP / 2; off; off >>= 1) p += __shfl_xor(p, off, 64);
            float mn    = fmaxf(m, p);
            float scale = __expf(m - mn);                  // first edge: exp(-inf)=0
            float w     = __expf(p - mn);
            l = l * scale + w;
#pragma unroll
            for (int k = 0; k < PER; ++k) acc[k] = fmaf(acc[k], scale, w * xls[k]);
            m = mn;
        }
    }
    float inv = 1.f / (l + 1e-16f);
    float o[PER];
#pragma unroll
    for (int k = 0; k < PER; ++k) {
        float v = fmaf(acc[k], inv, gbias[base + k]);
        float g  = bnp[base + k], be = bnp[HC + base + k];
        float mm = bnp[2 * HC + base + k], va = bnp[3 * HC + base + k];
        v = g * (v - mm) * rsqrtf(va + 1e-5f) + be;
        o[k] = (v > 0.f) ? v : (__expf(v) - 1.f);          // elu
    }
    if constexpr (PER == 4)
        *(float4*)(out + (size_t)node * HC + base) = *(float4*)o;
    else
        *(float2*)(out + (size_t)node * HC + base) = *(float2*)o;
}

// ---------------------------------------------------------------------------
// per-graph pooling (batch is sorted -> contiguous node ranges), no atomics
// ---------------------------------------------------------------------------
__global__ void pool_graph(const float* __restrict__ h, const int* __restrict__ gstart,
                           float* __restrict__ gbuf) {
    int g = blockIdx.x;
    int t = threadIdx.x;                   // 0..127
    int a = gstart[g], b = gstart[g + 1];
    float sum = 0.f, mx = -INFINITY;
    for (int i = a; i < b; ++i) {
        float v = h[(size_t)i * 128 + t];
        sum += v;
        mx = fmaxf(mx, v);
    }
    float cnt = fmaxf((float)(b - a), 1.f);
    gbuf[g * 256 + t]       = sum / cnt;
    gbuf[g * 256 + 128 + t] = (b > a) ? mx : 0.f;
}

// ---------------------------------------------------------------------------
// classifier head: one block (128 threads) per graph
// ---------------------------------------------------------------------------
__global__ void classifier(const float* __restrict__ g,
                           const float* __restrict__ w1, const float* __restrict__ b1,
                           const float* __restrict__ bnp,
                           const float* __restrict__ w2, const float* __restrict__ b2,
                           const float* __restrict__ w3, const float* __restrict__ b3,
                           float* __restrict__ out) {
    __shared__ float sg[256];
    __shared__ float sz1[128];
    __shared__ float sz2[64];
    __shared__ float sz3[2];
    int b = blockIdx.x, t = threadIdx.x;
    sg[t]       = g[b * 256 + t];
    sg[128 + t] = g[b * 256 + 128 + t];
    __syncthreads();
    float acc = b1[t];
    for (int i = 0; i < 256; ++i) acc += sg[i] * w1[i * 128 + t];
    float ga = bnp[t], be = bnp[128 + t], m = bnp[256 + t], va = bnp[384 + t];
    acc = ga * (acc - m) * rsqrtf(va + 1e-5f) + be;
    sz1[t] = fmaxf(acc, 0.f);
    __syncthreads();
    if (t < 64) {
        float a2 = b2[t];
        for (int i = 0; i < 128; ++i) a2 += sz1[i] * w2[i * 64 + t];
        sz2[t] = fmaxf(a2, 0.f);
    }
    __syncthreads();
    if (t < 2) {
        float a3 = b3[t];
        for (int i = 0; i < 64; ++i) a3 += sz2[i] * w3[i * 2 + t];
        sz3[t] = a3;
    }
    __syncthreads();
    if (t < 2) {
        float mm = fmaxf(sz3[0], sz3[1]);
        float lse = mm + logf(expf(sz3[0] - mm) + expf(sz3[1] - mm));
        out[b * 2 + t] = sz3[t] - lse;
    }
}

// ---------------------------------------------------------------------------
// launch
// ---------------------------------------------------------------------------
static inline int cdiv(int a, int b) { return (a + b - 1) / b; }

extern "C" void kernel_launch(void* const* d_in, const int* in_sizes, int n_in,
                              void* d_out, int out_size, void* d_ws, size_t ws_size,
                              hipStream_t stream) {
    const float* x       = (const float*)d_in[0];
    const int*   ei      = (const int*)d_in[1];
    const int*   batch   = (const int*)d_in[2];
    const float* w_in    = (const float*)d_in[3];
    const float* b_in    = (const float*)d_in[4];
    const float* bn_in   = (const float*)d_in[5];
    const float* g1_wl   = (const float*)d_in[6];
    const float* g1_bl   = (const float*)d_in[7];
    const float* g1_wr   = (const float*)d_in[8];
    const float* g1_br   = (const float*)d_in[9];
    const float* g1_att  = (const float*)d_in[10];
    const float* g1_bias = (const float*)d_in[11];
    const float* bn1     = (const float*)d_in[12];
    const float* g2_wl   = (const float*)d_in[13];
    const float* g2_bl   = (const float*)d_in[14];
    const float* g2_wr   = (const float*)d_in[15];
    const float* g2_br   = (const float*)d_in[16];
    const float* g2_att  = (const float*)d_in[17];
    const float* g2_bias = (const float*)d_in[18];
    const float* bn2     = (const float*)d_in[19];
    const float* g3_wl   = (const float*)d_in[20];
    const float* g3_bl   = (const float*)d_in[21];
    const float* g3_wr   = (const float*)d_in[22];
    const float* g3_br   = (const float*)d_in[23];
    const float* g3_att  = (const float*)d_in[24];
    const float* g3_bias = (const float*)d_in[25];
    const float* bn3     = (const float*)d_in[26];
    const float* c_w1    = (const float*)d_in[27];
    const float* c_b1    = (const float*)d_in[28];
    const float* c_bn    = (const float*)d_in[29];
    const float* c_w2    = (const float*)d_in[30];
    const float* c_b2    = (const float*)d_in[31];
    const float* c_w3    = (const float*)d_in[32];
    const float* c_b3    = (const float*)d_in[33];
    float* out = (float*)d_out;

    // ---- workspace layout
    float* ws = (float*)d_ws;
    const size_t NHC = (size_t)N_NODES * 256;       // 7,680,000
    float* bufA = ws;                               // node feature buffers
    float* bufB = ws + NHC;
    float* bufC = ws + 2 * NHC;
    float* bufD = ws + 3 * NHC;
    float* gbuf = ws + 4 * NHC;                     // 300*256
    int*   iw   = (int*)(ws + 4 * NHC + N_GRAPHS * 256);
    int* deg       = iw;                            // 30000
    int* cnt       = iw + 30000;                    // 30000 (scatter cursors)
    int* slocal    = iw + 60000;                    // 30000 (scan scratch)
    int* bsums     = iw + 90000;                    // 128
    int* row_start = iw + 90128;                    // 30001
    int* esrc      = iw + 120129;                   // 270000
    int* gdeg      = iw + 390129;                   // 300
    int* glocal    = iw + 390429;                   // 300
    int* gbsums    = iw + 390729;                   // 8
    int* gstart    = iw + 390737;                   // 301

    const int BT = 256;
    const int NTILES = cdiv(N_NODES, 128);          // 235

    // ---- CSR build by destination (same graph for all 3 layers)
    ifill<<<cdiv(60000, BT), BT, 0, stream>>>(deg, 0, 60000);        // deg + cnt
    ifill<<<cdiv(300, BT), BT, 0, stream>>>(gdeg, 0, 300);
    hist_edges<<<cdiv(E_TOT, BT), BT, 0, stream>>>(ei, deg);
    hist_batch<<<cdiv(N_NODES, BT), BT, 0, stream>>>(batch, gdeg);
    scan_partial<<<cdiv(N_NODES, 256), 256, 0, stream>>>(deg, slocal, bsums, N_NODES);
    scan_tops<<<1, 128, 0, stream>>>(bsums, cdiv(N_NODES, 256));
    scan_add<<<cdiv(N_NODES, BT), BT, 0, stream>>>(slocal, bsums, row_start, N_NODES, E_TOT);
    csr_scatter<<<cdiv(E_TOT, BT), BT, 0, stream>>>(ei, row_start, cnt, esrc);
    scan_partial<<<cdiv(N_GRAPHS, 256), 256, 0, stream>>>(gdeg, glocal, gbsums, N_GRAPHS);
    scan_tops<<<1, 128, 0, stream>>>(gbsums, cdiv(N_GRAPHS, 256));
    scan_add<<<cdiv(N_GRAPHS, BT), BT, 0, stream>>>(glocal, gbsums, gstart, N_GRAPHS, N_NODES);

    // ---- input layer: h0 = relu(bn(x @ w_in + b_in))  -> bufA (N x 64)
    node_gemm<5, 64, 4><<<cdiv(N_NODES, 4), 64, 0, stream>>>(x, w_in, b_in, bufA, bn_in, N_NODES, 1);

    // ---- GAT layer 1: 64 -> 4x64, in bufA, out bufD (fused aggr+bias+bn+elu)
    gemm_tiled<64, 256><<<dim3(NTILES, 2), 256, 0, stream>>>(bufA, g1_wl, g1_bl, bufB, N_NODES);
    gemm_tiled<64, 256><<<dim3(NTILES, 2), 256, 0, stream>>>(bufA, g1_wr, g1_br, bufC, N_NODES);
    gat_gather<4, 64><<<cdiv(N_NODES * 64, BT), BT, 0, stream>>>(bufB, bufC, row_start, esrc, g1_att, g1_bias, bn1, bufD);

    // ---- GAT layer 2: 256 -> 4x64, in bufD, out bufA
    gemm_tiled<256, 256><<<dim3(NTILES, 2), 256, 0, stream>>>(bufD, g2_wl, g2_bl, bufB, N_NODES);
    gemm_tiled<256, 256><<<dim3(NTILES, 2), 256, 0, stream>>>(bufD, g2_wr, g2_br, bufC, N_NODES);
    gat_gather<4, 64><<<cdiv(N_NODES * 64, BT), BT, 0, stream>>>(bufB, bufC, row_start, esrc, g2_att, g2_bias, bn2, bufA);

    // ---- GAT layer 3: 256 -> 1x128, in bufA, out bufD (N x 128)
    gemm_tiled<256, 128><<<dim3(NTILES, 1), 256, 0, stream>>>(bufA, g3_wl, g3_bl, bufB, N_NODES);
    gemm_tiled<256, 128><<<dim3(NTILES, 1), 256, 0, stream>>>(bufA, g3_wr, g3_br, bufC, N_NODES);
    gat_gather<1, 128><<<cdiv(N_NODES * 64, BT), BT, 0, stream>>>(bufB, bufC, row_start, esrc, g3_att, g3_bias, bn3, bufD);

    // ---- pooling: mean + max per graph -> gbuf (300 x 256), contiguous ranges
    pool_graph<<<N_GRAPHS, 128, 0, stream>>>(bufD, gstart, gbuf);

    // ---- classifier head
    classifier<<<N_GRAPHS, 128, 0, stream>>>(gbuf, c_w1, c_b1, c_bn, c_w2, c_b2, c_w3, c_b3, out);
}

// Round 5
// 602.175 us; speedup vs baseline: 5.8569x; 1.0465x over previous
//
#include <hip/hip_runtime.h>
#include <math.h>

#define N_NODES  30000
#define N_EDGES  240000
#define E_TOT    270000   // N_EDGES + N_NODES self loops
#define N_GRAPHS 300

// ---------------------------------------------------------------------------
// small utility kernels
// ---------------------------------------------------------------------------
__global__ void ifill(int* __restrict__ p, int v, int n) {
    int i = blockIdx.x * blockDim.x + threadIdx.x;
    if (i < n) p[i] = v;
}

// ---------------------------------------------------------------------------
// CSR build: histogram -> two-level exclusive scan -> scatter
// ---------------------------------------------------------------------------
__global__ void hist_edges(const int* __restrict__ ei, int* __restrict__ deg) {
    int e = blockIdx.x * blockDim.x + threadIdx.x;
    if (e >= E_TOT) return;
    int d = (e < N_EDGES) ? ei[N_EDGES + e] : e - N_EDGES;
    atomicAdd(&deg[d], 1);
}

__global__ void hist_batch(const int* __restrict__ batch, int* __restrict__ gdeg) {
    int i = blockIdx.x * blockDim.x + threadIdx.x;
    if (i < N_NODES) atomicAdd(&gdeg[batch[i]], 1);
}

// per-block exclusive scan of 256-chunks; writes block sums
__global__ void scan_partial(const int* __restrict__ in, int* __restrict__ local,
                             int* __restrict__ bsums, int n) {
    __shared__ int s[256];
    int t = threadIdx.x;
    int gid = blockIdx.x * 256 + t;
    int v = (gid < n) ? in[gid] : 0;
    s[t] = v;
    __syncthreads();
    for (int off = 1; off < 256; off <<= 1) {
        int u = (t >= off) ? s[t - off] : 0;
        __syncthreads();
        s[t] += u;
        __syncthreads();
    }
    if (gid < n) local[gid] = s[t] - v;           // exclusive
    if (t == 255) bsums[blockIdx.x] = s[255];
}

// single-block exclusive scan of block sums (nb <= 128)
__global__ void scan_tops(int* __restrict__ bsums, int nb) {
    __shared__ int s[128];
    int t = threadIdx.x;
    int v = (t < nb) ? bsums[t] : 0;
    s[t] = v;
    __syncthreads();
    for (int off = 1; off < 128; off <<= 1) {
        int u = (t >= off) ? s[t - off] : 0;
        __syncthreads();
        s[t] += u;
        __syncthreads();
    }
    if (t < nb) bsums[t] = s[t] - v;              // exclusive offsets
}

__global__ void scan_add(const int* __restrict__ local, const int* __restrict__ bsums,
                         int* __restrict__ out, int n, int total) {
    int gid = blockIdx.x * blockDim.x + threadIdx.x;
    if (gid < n) out[gid] = local[gid] + bsums[gid >> 8];
    if (gid == 0) out[n] = total;
}

__global__ void csr_scatter(const int* __restrict__ ei, const int* __restrict__ row_start,
                            int* __restrict__ cnt, int* __restrict__ esrc) {
    int e = blockIdx.x * blockDim.x + threadIdx.x;
    if (e >= E_TOT) return;
    int s, d;
    if (e < N_EDGES) { s = ei[e]; d = ei[N_EDGES + e]; }
    else             { s = e - N_EDGES; d = s; }
    int slot = row_start[d] + atomicAdd(&cnt[d], 1);
    esrc[slot] = s;
}

// ---------------------------------------------------------------------------
// fused pair GEMM: computes BOTH  outl = A@Wl+bl  and  outr = A@Wr+br
// blockIdx.y selects (W,bias,out) and 128-col slice -> 2x blocks in flight.
// BM x 128 tile, BK=32, 256 threads, (BM/16)x8 outputs/thread.
// Register double-buffered staging: next tile's global loads issued before
// compute so global latency overlaps the FMA loop.
// ---------------------------------------------------------------------------
template<int K, int COUT, int BM>
__global__ __launch_bounds__(256, 3)
void gemm_pair(const float* __restrict__ A,
               const float* __restrict__ Wl, const float* __restrict__ bl,
               const float* __restrict__ Wr, const float* __restrict__ br,
               float* __restrict__ outl, float* __restrict__ outr, int N) {
    constexpr int BN = 128, BK = 32;
    constexpr int RG = BM / 64;            // row groups per thread (2 or 1)
    constexpr int AV = BM / 32;            // float4 A loads per thread (4 or 2)
    __shared__ float As[BK][BM + 4];       // +4 keeps b128 alignment
    __shared__ float Bs[BK][BN];
    const int tid = threadIdx.x;
    const int tx = tid & 15;
    const int ty = tid >> 4;
    const int n0 = blockIdx.x * BM;
    constexpr int CSLICES = COUT / 128;
    const int sel  = blockIdx.y / CSLICES;
    const int col0 = (blockIdx.y % CSLICES) * 128;
    const float* W    = sel ? Wr : Wl;
    const float* bias = sel ? br : bl;
    float* out        = sel ? outr : outl;

    float acc[RG * 4][8];
#pragma unroll
    for (int r = 0; r < RG * 4; ++r)
#pragma unroll
        for (int c = 0; c < 8; ++c) acc[r][c] = 0.f;

    const int a_node = tid >> 3;           // 0..31
    const int a_k    = (tid & 7) * 4;      // 0..28
    const int b_k    = tid >> 5;           // 0..7
    const int b_c    = (tid & 31) * 4;     // 0..124

    float4 aregs[AV], bregs[4];
    auto load_tiles = [&](int kt) {
#pragma unroll
        for (int r = 0; r < AV; ++r) {
            int gn = n0 + r * 32 + a_node;
            aregs[r] = (gn < N) ? *(const float4*)(A + (size_t)gn * K + kt + a_k)
                                : make_float4(0.f, 0.f, 0.f, 0.f);
        }
#pragma unroll
        for (int r = 0; r < 4; ++r) {
            int k = r * 8 + b_k;
            bregs[r] = *(const float4*)(W + (size_t)(kt + k) * COUT + col0 + b_c);
        }
    };
    load_tiles(0);

    for (int kt = 0; kt < K; kt += BK) {
        // ---- commit staged regs to LDS
#pragma unroll
        for (int r = 0; r < AV; ++r) {
            int node = r * 32 + a_node;
            As[a_k + 0][node] = aregs[r].x;
            As[a_k + 1][node] = aregs[r].y;
            As[a_k + 2][node] = aregs[r].z;
            As[a_k + 3][node] = aregs[r].w;
        }
#pragma unroll
        for (int r = 0; r < 4; ++r)
            *(float4*)(&Bs[r * 8 + b_k][b_c]) = bregs[r];
        __syncthreads();
        // ---- issue next tile's global loads (overlap with compute)
        if (kt + BK < K) load_tiles(kt + BK);
        // ---- FMA loop
#pragma unroll 4
        for (int k = 0; k < BK; ++k) {
            float a[RG * 4], b[8];
            *(float4*)(a) = *(const float4*)(&As[k][ty * 4]);
            if constexpr (RG == 2)
                *(float4*)(a + 4) = *(const float4*)(&As[k][64 + ty * 4]);
            *(float4*)(b)     = *(const float4*)(&Bs[k][tx * 4]);
            *(float4*)(b + 4) = *(const float4*)(&Bs[k][64 + tx * 4]);
#pragma unroll
            for (int r = 0; r < RG * 4; ++r)
#pragma unroll
                for (int c = 0; c < 8; ++c) acc[r][c] += a[r] * b[c];
        }
        __syncthreads();
    }
    // ---- epilogue: + bias, coalesced float4 stores
#pragma unroll
    for (int g = 0; g < RG; ++g)
#pragma unroll
        for (int r = 0; r < 4; ++r) {
            int row = n0 + g * 64 + ty * 4 + r;
            if (row >= N) continue;
#pragma unroll
            for (int cc = 0; cc < 2; ++cc) {
                int col = col0 + cc * 64 + tx * 4;
                float4 v;
                v.x = acc[g * 4 + r][cc * 4 + 0] + bias[col + 0];
                v.y = acc[g * 4 + r][cc * 4 + 1] + bias[col + 1];
                v.z = acc[g * 4 + r][cc * 4 + 2] + bias[col + 2];
                v.w = acc[g * 4 + r][cc * 4 + 3] + bias[col + 3];
                *(float4*)(out + (size_t)row * COUT + col) = v;
            }
        }
}

// ---------------------------------------------------------------------------
// input layer GEMM (tiny K=5)
// ---------------------------------------------------------------------------
template<int CIN, int COUT, int NT>
__global__ void node_gemm(const float* __restrict__ h, const float* __restrict__ W,
                          const float* __restrict__ bias, float* __restrict__ out,
                          const float* __restrict__ bnp, int n_nodes, int act) {
    __shared__ float sh[NT][CIN];
    const int n0 = blockIdx.x * NT;
    const int t  = threadIdx.x;
    for (int i = t; i < NT * CIN; i += COUT) {
        int nn = i / CIN, ci = i - nn * CIN;
        int n = n0 + nn;
        sh[nn][ci] = (n < n_nodes) ? h[(size_t)n * CIN + ci] : 0.f;
    }
    __syncthreads();
    float acc[NT];
#pragma unroll
    for (int j = 0; j < NT; ++j) acc[j] = bias[t];
    for (int ci = 0; ci < CIN; ++ci) {
        float w = W[ci * COUT + t];
#pragma unroll
        for (int j = 0; j < NT; ++j) acc[j] += sh[j][ci] * w;
    }
#pragma unroll
    for (int j = 0; j < NT; ++j) {
        int n = n0 + j;
        if (n >= n_nodes) break;
        float v = acc[j];
        if (act == 1) {
            float g = bnp[t], be = bnp[COUT + t], m = bnp[2 * COUT + t], va = bnp[3 * COUT + t];
            v = g * (v - m) * rsqrtf(va + 1e-5f) + be;
            v = fmaxf(v, 0.f);
        }
        out[(size_t)n * COUT + t] = v;
    }
}

// ---------------------------------------------------------------------------
// fused GATv2 gather: ONE WAVE PER NODE covering all H heads (HC channels).
// Online softmax per head; edge indices prefetched coalesced + broadcast.
// Epilogue: bias + bn + elu. No atomics.
// ---------------------------------------------------------------------------
template<int H, int C>
__global__ __launch_bounds__(256)
void gat_gather(const float* __restrict__ xl, const float* __restrict__ xr,
                const int* __restrict__ row_start, const int* __restrict__ esrc,
                const float* __restrict__ att, const float* __restrict__ gbias,
                const float* __restrict__ bnp, float* __restrict__ out) {
    constexpr int HC    = H * C;
    constexpr int PER   = HC / 64;         // channels per lane (4 or 2)
    constexpr int GROUP = 64 / H;          // lanes per head (16 or 64)
    int node = (blockIdx.x * blockDim.x + threadIdx.x) >> 6;
    int lane = threadIdx.x & 63;
    if (node >= N_NODES) return;
    const int base = lane * PER;

    float rr[PER], av[PER], acc[PER];
    if constexpr (PER == 4) {
        *(float4*)rr = *(const float4*)(xr + (size_t)node * HC + base);
        *(float4*)av = *(const float4*)(att + base);
    } else {
        *(float2*)rr = *(const float2*)(xr + (size_t)node * HC + base);
        *(float2*)av = *(const float2*)(att + base);
    }
#pragma unroll
    for (int k = 0; k < PER; ++k) acc[k] = 0.f;

    float m = -INFINITY, l = 0.f;
    const int j0 = row_start[node], j1 = row_start[node + 1];
    for (int jc = j0; jc < j1; jc += 64) {
        int nedge = min(64, j1 - jc);
        int ev = (jc + lane < j1) ? esrc[jc + lane] : 0;   // coalesced prefetch
        for (int jj = 0; jj < nedge; ++jj) {
            int s = __shfl(ev, jj, 64);                    // broadcast edge src
            float xls[PER];
            if constexpr (PER == 4)
                *(float4*)xls = *(const float4*)(xl + (size_t)s * HC + base);
            else
                *(float2*)xls = *(const float2*)(xl + (size_t)s * HC + base);
            float p = 0.f;
#pragma unroll
            for (int k = 0; k < PER; ++k) {
                float v = xls[k] + rr[k];
                v = (v > 0.f) ? v : 0.2f * v;              // leaky_relu 0.2
                p = fmaf(v, av[k], p);
            }
#pragma unroll
            for (int off = GROUP / 2; off; off >>= 1) p += __shfl_xor(p, off, 64);
            float mn    = fmaxf(m, p);
            float scale = __expf(m - mn);                  // first edge: exp(-inf)=0
            float w     = __expf(p - mn);
            l = l * scale + w;
#pragma unroll
            for (int k = 0; k < PER; ++k) acc[k] = fmaf(acc[k], scale, w * xls[k]);
            m = mn;
        }
    }
    float inv = 1.f / (l + 1e-16f);
    float o[PER];
#pragma unroll
    for (int k = 0; k < PER; ++k) {
        float v = fmaf(acc[k], inv, gbias[base + k]);
        float g  = bnp[base + k], be = bnp[HC + base + k];
        float mm = bnp[2 * HC + base + k], va = bnp[3 * HC + base + k];
        v = g * (v - mm) * rsqrtf(va + 1e-5f) + be;
        o[k] = (v > 0.f) ? v : (__expf(v) - 1.f);          // elu
    }
    if constexpr (PER == 4)
        *(float4*)(out + (size_t)node * HC + base) = *(float4*)o;
    else
        *(float2*)(out + (size_t)node * HC + base) = *(float2*)o;
}

// ---------------------------------------------------------------------------
// per-graph pooling (batch is sorted -> contiguous node ranges), no atomics
// ---------------------------------------------------------------------------
__global__ void pool_graph(const float* __restrict__ h, const int* __restrict__ gstart,
                           float* __restrict__ gbuf) {
    int g = blockIdx.x;
    int t = threadIdx.x;                   // 0..127
    int a = gstart[g], b = gstart[g + 1];
    float sum = 0.f, mx = -INFINITY;
    for (int i = a; i < b; ++i) {
        float v = h[(size_t)i * 128 + t];
        sum += v;
        mx = fmaxf(mx, v);
    }
    float cnt = fmaxf((float)(b - a), 1.f);
    gbuf[g * 256 + t]       = sum / cnt;
    gbuf[g * 256 + 128 + t] = (b > a) ? mx : 0.f;
}

// ---------------------------------------------------------------------------
// classifier head: one block (128 threads) per graph
// ---------------------------------------------------------------------------
__global__ void classifier(const float* __restrict__ g,
                           const float* __restrict__ w1, const float* __restrict__ b1,
                           const float* __restrict__ bnp,
                           const float* __restrict__ w2, const float* __restrict__ b2,
                           const float* __restrict__ w3, const float* __restrict__ b3,
                           float* __restrict__ out) {
    __shared__ float sg[256];
    __shared__ float sz1[128];
    __shared__ float sz2[64];
    __shared__ float sz3[2];
    int b = blockIdx.x, t = threadIdx.x;
    sg[t]       = g[b * 256 + t];
    sg[128 + t] = g[b * 256 + 128 + t];
    __syncthreads();
    float acc = b1[t];
    for (int i = 0; i < 256; ++i) acc += sg[i] * w1[i * 128 + t];
    float ga = bnp[t], be = bnp[128 + t], m = bnp[256 + t], va = bnp[384 + t];
    acc = ga * (acc - m) * rsqrtf(va + 1e-5f) + be;
    sz1[t] = fmaxf(acc, 0.f);
    __syncthreads();
    if (t < 64) {
        float a2 = b2[t];
        for (int i = 0; i < 128; ++i) a2 += sz1[i] * w2[i * 64 + t];
        sz2[t] = fmaxf(a2, 0.f);
    }
    __syncthreads();
    if (t < 2) {
        float a3 = b3[t];
        for (int i = 0; i < 64; ++i) a3 += sz2[i] * w3[i * 2 + t];
        sz3[t] = a3;
    }
    __syncthreads();
    if (t < 2) {
        float mm = fmaxf(sz3[0], sz3[1]);
        float lse = mm + logf(expf(sz3[0] - mm) + expf(sz3[1] - mm));
        out[b * 2 + t] = sz3[t] - lse;
    }
}

// ---------------------------------------------------------------------------
// launch
// ---------------------------------------------------------------------------
static inline int cdiv(int a, int b) { return (a + b - 1) / b; }

extern "C" void kernel_launch(void* const* d_in, const int* in_sizes, int n_in,
                              void* d_out, int out_size, void* d_ws, size_t ws_size,
                              hipStream_t stream) {
    const float* x       = (const float*)d_in[0];
    const int*   ei      = (const int*)d_in[1];
    const int*   batch   = (const int*)d_in[2];
    const float* w_in    = (const float*)d_in[3];
    const float* b_in    = (const float*)d_in[4];
    const float* bn_in   = (const float*)d_in[5];
    const float* g1_wl   = (const float*)d_in[6];
    const float* g1_bl   = (const float*)d_in[7];
    const float* g1_wr   = (const float*)d_in[8];
    const float* g1_br   = (const float*)d_in[9];
    const float* g1_att  = (const float*)d_in[10];
    const float* g1_bias = (const float*)d_in[11];
    const float* bn1     = (const float*)d_in[12];
    const float* g2_wl   = (const float*)d_in[13];
    const float* g2_bl   = (const float*)d_in[14];
    const float* g2_wr   = (const float*)d_in[15];
    const float* g2_br   = (const float*)d_in[16];
    const float* g2_att  = (const float*)d_in[17];
    const float* g2_bias = (const float*)d_in[18];
    const float* bn2     = (const float*)d_in[19];
    const float* g3_wl   = (const float*)d_in[20];
    const float* g3_bl   = (const float*)d_in[21];
    const float* g3_wr   = (const float*)d_in[22];
    const float* g3_br   = (const float*)d_in[23];
    const float* g3_att  = (const float*)d_in[24];
    const float* g3_bias = (const float*)d_in[25];
    const float* bn3     = (const float*)d_in[26];
    const float* c_w1    = (const float*)d_in[27];
    const float* c_b1    = (const float*)d_in[28];
    const float* c_bn    = (const float*)d_in[29];
    const float* c_w2    = (const float*)d_in[30];
    const float* c_b2    = (const float*)d_in[31];
    const float* c_w3    = (const float*)d_in[32];
    const float* c_b3    = (const float*)d_in[33];
    float* out = (float*)d_out;

    // ---- workspace layout
    float* ws = (float*)d_ws;
    const size_t NHC = (size_t)N_NODES * 256;       // 7,680,000
    float* bufA = ws;                               // node feature buffers
    float* bufB = ws + NHC;
    float* bufC = ws + 2 * NHC;
    float* bufD = ws + 3 * NHC;
    float* gbuf = ws + 4 * NHC;                     // 300*256
    int*   iw   = (int*)(ws + 4 * NHC + N_GRAPHS * 256);
    int* deg       = iw;                            // 30000
    int* cnt       = iw + 30000;                    // 30000 (scatter cursors)
    int* slocal    = iw + 60000;                    // 30000 (scan scratch)
    int* bsums     = iw + 90000;                    // 128
    int* row_start = iw + 90128;                    // 30001
    int* esrc      = iw + 120129;                   // 270000
    int* gdeg      = iw + 390129;                   // 300
    int* glocal    = iw + 390429;                   // 300
    int* gbsums    = iw + 390729;                   // 8
    int* gstart    = iw + 390737;                   // 301

    const int BT = 256;

    // ---- CSR build by destination (same graph for all 3 layers)
    ifill<<<cdiv(60000, BT), BT, 0, stream>>>(deg, 0, 60000);        // deg + cnt
    ifill<<<cdiv(300, BT), BT, 0, stream>>>(gdeg, 0, 300);
    hist_edges<<<cdiv(E_TOT, BT), BT, 0, stream>>>(ei, deg);
    hist_batch<<<cdiv(N_NODES, BT), BT, 0, stream>>>(batch, gdeg);
    scan_partial<<<cdiv(N_NODES, 256), 256, 0, stream>>>(deg, slocal, bsums, N_NODES);
    scan_tops<<<1, 128, 0, stream>>>(bsums, cdiv(N_NODES, 256));
    scan_add<<<cdiv(N_NODES, BT), BT, 0, stream>>>(slocal, bsums, row_start, N_NODES, E_TOT);
    csr_scatter<<<cdiv(E_TOT, BT), BT, 0, stream>>>(ei, row_start, cnt, esrc);
    scan_partial<<<cdiv(N_GRAPHS, 256), 256, 0, stream>>>(gdeg, glocal, gbsums, N_GRAPHS);
    scan_tops<<<1, 128, 0, stream>>>(gbsums, cdiv(N_GRAPHS, 256));
    scan_add<<<cdiv(N_GRAPHS, BT), BT, 0, stream>>>(glocal, gbsums, gstart, N_GRAPHS, N_NODES);

    // ---- input layer: h0 = relu(bn(x @ w_in + b_in))  -> bufA (N x 64)
    node_gemm<5, 64, 4><<<cdiv(N_NODES, 4), 64, 0, stream>>>(x, w_in, b_in, bufA, bn_in, N_NODES, 1);

    // ---- GAT layer 1: 64 -> 4x64, in bufA, out bufD (fused pair + gather)
    gemm_pair<64, 256, 128><<<dim3(cdiv(N_NODES, 128), 4), 256, 0, stream>>>(
        bufA, g1_wl, g1_bl, g1_wr, g1_br, bufB, bufC, N_NODES);
    gat_gather<4, 64><<<cdiv(N_NODES * 64, BT), BT, 0, stream>>>(bufB, bufC, row_start, esrc, g1_att, g1_bias, bn1, bufD);

    // ---- GAT layer 2: 256 -> 4x64, in bufD, out bufA
    gemm_pair<256, 256, 128><<<dim3(cdiv(N_NODES, 128), 4), 256, 0, stream>>>(
        bufD, g2_wl, g2_bl, g2_wr, g2_br, bufB, bufC, N_NODES);
    gat_gather<4, 64><<<cdiv(N_NODES * 64, BT), BT, 0, stream>>>(bufB, bufC, row_start, esrc, g2_att, g2_bias, bn2, bufA);

    // ---- GAT layer 3: 256 -> 1x128, in bufA, out bufD (N x 128); BM=64 for blocks
    gemm_pair<256, 128, 64><<<dim3(cdiv(N_NODES, 64), 2), 256, 0, stream>>>(
        bufA, g3_wl, g3_bl, g3_wr, g3_br, bufB, bufC, N_NODES);
    gat_gather<1, 128><<<cdiv(N_NODES * 64, BT), BT, 0, stream>>>(bufB, bufC, row_start, esrc, g3_att, g3_bias, bn3, bufD);

    // ---- pooling: mean + max per graph -> gbuf (300 x 256), contiguous ranges
    pool_graph<<<N_GRAPHS, 128, 0, stream>>>(bufD, gstart, gbuf);

    // ---- classifier head
    classifier<<<N_GRAPHS, 128, 0, stream>>>(gbuf, c_w1, c_b1, c_bn, c_w2, c_b2, c_w3, c_b3, out);
}

// Round 6
// 451.727 us; speedup vs baseline: 7.8076x; 1.3331x over previous
//
#include <hip/hip_runtime.h>
#include <math.h>

#define N_NODES  30000
#define N_EDGES  240000
#define E_TOT    270000   // N_EDGES + N_NODES self loops
#define N_GRAPHS 300

typedef _Float16 half8 __attribute__((ext_vector_type(8)));
typedef _Float16 half4 __attribute__((ext_vector_type(4)));
typedef _Float16 half2v __attribute__((ext_vector_type(2)));
typedef float float4v __attribute__((ext_vector_type(4)));

// ---------------------------------------------------------------------------
// small utility kernels
// ---------------------------------------------------------------------------
__global__ void ifill(int* __restrict__ p, int v, int n) {
    int i = blockIdx.x * blockDim.x + threadIdx.x;
    if (i < n) p[i] = v;
}

// weight prep: W[K][COUT] f32 -> Wt[COUT][K] f16 (transposed, converted)
template<int K, int COUT>
__global__ void wprep(const float* __restrict__ W, _Float16* __restrict__ Wt) {
    int i = blockIdx.x * blockDim.x + threadIdx.x;
    if (i >= K * COUT) return;
    int k = i / COUT, c = i - k * COUT;
    Wt[(size_t)c * K + k] = (_Float16)W[i];
}

// ---------------------------------------------------------------------------
// CSR build: histogram -> two-level exclusive scan -> scatter
// ---------------------------------------------------------------------------
__global__ void hist_edges(const int* __restrict__ ei, int* __restrict__ deg) {
    int e = blockIdx.x * blockDim.x + threadIdx.x;
    if (e >= E_TOT) return;
    int d = (e < N_EDGES) ? ei[N_EDGES + e] : e - N_EDGES;
    atomicAdd(&deg[d], 1);
}

__global__ void hist_batch(const int* __restrict__ batch, int* __restrict__ gdeg) {
    int i = blockIdx.x * blockDim.x + threadIdx.x;
    if (i < N_NODES) atomicAdd(&gdeg[batch[i]], 1);
}

__global__ void scan_partial(const int* __restrict__ in, int* __restrict__ local,
                             int* __restrict__ bsums, int n) {
    __shared__ int s[256];
    int t = threadIdx.x;
    int gid = blockIdx.x * 256 + t;
    int v = (gid < n) ? in[gid] : 0;
    s[t] = v;
    __syncthreads();
    for (int off = 1; off < 256; off <<= 1) {
        int u = (t >= off) ? s[t - off] : 0;
        __syncthreads();
        s[t] += u;
        __syncthreads();
    }
    if (gid < n) local[gid] = s[t] - v;           // exclusive
    if (t == 255) bsums[blockIdx.x] = s[255];
}

__global__ void scan_tops(int* __restrict__ bsums, int nb) {
    __shared__ int s[128];
    int t = threadIdx.x;
    int v = (t < nb) ? bsums[t] : 0;
    s[t] = v;
    __syncthreads();
    for (int off = 1; off < 128; off <<= 1) {
        int u = (t >= off) ? s[t - off] : 0;
        __syncthreads();
        s[t] += u;
        __syncthreads();
    }
    if (t < nb) bsums[t] = s[t] - v;
}

__global__ void scan_add(const int* __restrict__ local, const int* __restrict__ bsums,
                         int* __restrict__ out, int n, int total) {
    int gid = blockIdx.x * blockDim.x + threadIdx.x;
    if (gid < n) out[gid] = local[gid] + bsums[gid >> 8];
    if (gid == 0) out[n] = total;
}

__global__ void csr_scatter(const int* __restrict__ ei, const int* __restrict__ row_start,
                            int* __restrict__ cnt, int* __restrict__ esrc) {
    int e = blockIdx.x * blockDim.x + threadIdx.x;
    if (e >= E_TOT) return;
    int s, d;
    if (e < N_EDGES) { s = ei[e]; d = ei[N_EDGES + e]; }
    else             { s = e - N_EDGES; d = s; }
    int slot = row_start[d] + atomicAdd(&cnt[d], 1);
    esrc[slot] = s;
}

// ---------------------------------------------------------------------------
// MFMA f16 pair GEMM: outl = A@Wl+bl, outr = A@Wr+br  (fp32 accumulate)
// A: [N][K] f16; Wt*: [COUT][K] f16 (pre-transposed). Tile BM=128 x BN=128,
// BK=64. 4 waves; wave w owns rows [32w,32w+32) as 2 m-tiles x 8 n-tiles of
// mfma_f32_16x16x32_f16. Verified layouts: A[m=lane&15][k=quad*8+j],
// B[k][n=lane&15] (same packing from Bs[n][k]), D col=lane&15 row=quad*4+r.
// ---------------------------------------------------------------------------
template<int K, int COUT>
__global__ __launch_bounds__(256, 3)
void gemm_mfma(const _Float16* __restrict__ A,
               const _Float16* __restrict__ Wtl, const float* __restrict__ bl,
               const _Float16* __restrict__ Wtr, const float* __restrict__ br,
               _Float16* __restrict__ outl, _Float16* __restrict__ outr, int N) {
    constexpr int BM = 128, BN = 128, BK = 64;
    constexpr int LDK = BK + 8;                 // pad: 2-way LDS aliasing only
    __shared__ _Float16 As[BM][LDK];
    __shared__ _Float16 Bs[BN][LDK];
    const int tid  = threadIdx.x;
    const int wave = tid >> 6;
    const int lane = tid & 63;
    const int l15  = lane & 15;
    const int lq   = lane >> 4;
    const int n0   = blockIdx.x * BM;
    constexpr int CSL = COUT / BN > 0 ? COUT / BN : 1;   // col slices (2 or 1)
    const int sel  = blockIdx.y / CSL;
    const int col0 = (blockIdx.y % CSL) * BN;
    const _Float16* Wt = sel ? Wtr : Wtl;
    const float* bias  = sel ? br : bl;
    _Float16* out      = sel ? outr : outl;

    float4v acc[2][8];
#pragma unroll
    for (int mi = 0; mi < 2; ++mi)
#pragma unroll
        for (int nt = 0; nt < 8; ++nt)
#pragma unroll
            for (int r = 0; r < 4; ++r) acc[mi][nt][r] = 0.f;

    for (int kt = 0; kt < K; kt += BK) {
        // ---- stage A tile: 128 rows x 64 f16, 4 passes x (256 thr x 8 f16)
#pragma unroll
        for (int p = 0; p < 4; ++p) {
            int idx = p * 256 + tid;
            int row = idx >> 3;
            int ch  = (idx & 7) * 8;
            int gn  = n0 + row;
            half8 v = {};
            if (gn < N) v = *(const half8*)(A + (size_t)gn * K + kt + ch);
            *(half8*)(&As[row][ch]) = v;
        }
        // ---- stage B tile from Wt (coalesced rows)
#pragma unroll
        for (int p = 0; p < 4; ++p) {
            int idx = p * 256 + tid;
            int row = idx >> 3;
            int ch  = (idx & 7) * 8;
            half8 v = *(const half8*)(Wt + (size_t)(col0 + row) * K + kt + ch);
            *(half8*)(&Bs[row][ch]) = v;
        }
        __syncthreads();
#pragma unroll
        for (int kk = 0; kk < BK; kk += 32) {
            half8 af0 = *(const half8*)(&As[wave * 32 + l15][kk + lq * 8]);
            half8 af1 = *(const half8*)(&As[wave * 32 + 16 + l15][kk + lq * 8]);
#pragma unroll
            for (int nt = 0; nt < 8; ++nt) {
                half8 bf = *(const half8*)(&Bs[nt * 16 + l15][kk + lq * 8]);
                acc[0][nt] = __builtin_amdgcn_mfma_f32_16x16x32_f16(af0, bf, acc[0][nt], 0, 0, 0);
                acc[1][nt] = __builtin_amdgcn_mfma_f32_16x16x32_f16(af1, bf, acc[1][nt], 0, 0, 0);
            }
        }
        __syncthreads();
    }
    // ---- epilogue: +bias, f16 store
#pragma unroll
    for (int mi = 0; mi < 2; ++mi)
#pragma unroll
        for (int nt = 0; nt < 8; ++nt) {
            int col = col0 + nt * 16 + l15;
            float bv = bias[col];
#pragma unroll
            for (int r = 0; r < 4; ++r) {
                int row = n0 + wave * 32 + mi * 16 + lq * 4 + r;
                if (row < N)
                    out[(size_t)row * COUT + col] = (_Float16)(acc[mi][nt][r] + bv);
            }
        }
}

// ---------------------------------------------------------------------------
// input layer GEMM (tiny K=5): f32 math, bn+relu, emits f16 [N][64]
// ---------------------------------------------------------------------------
template<int CIN, int COUT, int NT>
__global__ void node_gemm(const float* __restrict__ h, const float* __restrict__ W,
                          const float* __restrict__ bias, _Float16* __restrict__ out,
                          const float* __restrict__ bnp, int n_nodes) {
    __shared__ float sh[NT][CIN];
    const int n0 = blockIdx.x * NT;
    const int t  = threadIdx.x;
    for (int i = t; i < NT * CIN; i += COUT) {
        int nn = i / CIN, ci = i - nn * CIN;
        int n = n0 + nn;
        sh[nn][ci] = (n < n_nodes) ? h[(size_t)n * CIN + ci] : 0.f;
    }
    __syncthreads();
    float acc[NT];
#pragma unroll
    for (int j = 0; j < NT; ++j) acc[j] = bias[t];
    for (int ci = 0; ci < CIN; ++ci) {
        float w = W[ci * COUT + t];
#pragma unroll
        for (int j = 0; j < NT; ++j) acc[j] += sh[j][ci] * w;
    }
#pragma unroll
    for (int j = 0; j < NT; ++j) {
        int n = n0 + j;
        if (n >= n_nodes) break;
        float v = acc[j];
        float g = bnp[t], be = bnp[COUT + t], m = bnp[2 * COUT + t], va = bnp[3 * COUT + t];
        v = g * (v - m) * rsqrtf(va + 1e-5f) + be;
        v = fmaxf(v, 0.f);
        out[(size_t)n * COUT + t] = (_Float16)v;
    }
}

// ---------------------------------------------------------------------------
// fused GATv2 gather: one wave per node, all H heads. f16 features in,
// fp32 math, online softmax per head, bias+bn+elu epilogue, TOUT out.
// ---------------------------------------------------------------------------
template<int H, int C, typename TOUT>
__global__ __launch_bounds__(256)
void gat_gather(const _Float16* __restrict__ xl, const _Float16* __restrict__ xr,
                const int* __restrict__ row_start, const int* __restrict__ esrc,
                const float* __restrict__ att, const float* __restrict__ gbias,
                const float* __restrict__ bnp, TOUT* __restrict__ out) {
    constexpr int HC    = H * C;
    constexpr int PER   = HC / 64;         // channels per lane (4 or 2)
    constexpr int GROUP = 64 / H;          // lanes per head (16 or 64)
    int node = (blockIdx.x * blockDim.x + threadIdx.x) >> 6;
    int lane = threadIdx.x & 63;
    if (node >= N_NODES) return;
    const int base = lane * PER;

    float rr[PER], av[PER], acc[PER];
    if constexpr (PER == 4) {
        half4 rv = *(const half4*)(xr + (size_t)node * HC + base);
#pragma unroll
        for (int k = 0; k < PER; ++k) rr[k] = (float)rv[k];
        *(float4*)av = *(const float4*)(att + base);
    } else {
        half2v rv = *(const half2v*)(xr + (size_t)node * HC + base);
#pragma unroll
        for (int k = 0; k < PER; ++k) rr[k] = (float)rv[k];
        *(float2*)av = *(const float2*)(att + base);
    }
#pragma unroll
    for (int k = 0; k < PER; ++k) acc[k] = 0.f;

    float m = -INFINITY, l = 0.f;
    const int j0 = row_start[node], j1 = row_start[node + 1];
    for (int jc = j0; jc < j1; jc += 64) {
        int nedge = min(64, j1 - jc);
        int ev = (jc + lane < j1) ? esrc[jc + lane] : 0;   // coalesced prefetch
        for (int jj = 0; jj < nedge; ++jj) {
            int s = __shfl(ev, jj, 64);                    // broadcast edge src
            float xls[PER];
            if constexpr (PER == 4) {
                half4 xv = *(const half4*)(xl + (size_t)s * HC + base);
#pragma unroll
                for (int k = 0; k < PER; ++k) xls[k] = (float)xv[k];
            } else {
                half2v xv = *(const half2v*)(xl + (size_t)s * HC + base);
#pragma unroll
                for (int k = 0; k < PER; ++k) xls[k] = (float)xv[k];
            }
            float p = 0.f;
#pragma unroll
            for (int k = 0; k < PER; ++k) {
                float v = xls[k] + rr[k];
                v = (v > 0.f) ? v : 0.2f * v;              // leaky_relu 0.2
                p = fmaf(v, av[k], p);
            }
#pragma unroll
            for (int off = GROUP / 2; off; off >>= 1) p += __shfl_xor(p, off, 64);
            float mn    = fmaxf(m, p);
            float scale = __expf(m - mn);                  // first edge: exp(-inf)=0
            float w     = __expf(p - mn);
            l = l * scale + w;
#pragma unroll
            for (int k = 0; k < PER; ++k) acc[k] = fmaf(acc[k], scale, w * xls[k]);
            m = mn;
        }
    }
    float inv = 1.f / (l + 1e-16f);
    float o[PER];
#pragma unroll
    for (int k = 0; k < PER; ++k) {
        float v = fmaf(acc[k], inv, gbias[base + k]);
        float g  = bnp[base + k], be = bnp[HC + base + k];
        float mm = bnp[2 * HC + base + k], va = bnp[3 * HC + base + k];
        v = g * (v - mm) * rsqrtf(va + 1e-5f) + be;
        o[k] = (v > 0.f) ? v : (__expf(v) - 1.f);          // elu
    }
    if constexpr (sizeof(TOUT) == 2) {
        if constexpr (PER == 4) {
            half4 ov;
#pragma unroll
            for (int k = 0; k < PER; ++k) ov[k] = (_Float16)o[k];
            *(half4*)((_Float16*)out + (size_t)node * HC + base) = ov;
        } else {
            half2v ov;
#pragma unroll
            for (int k = 0; k < PER; ++k) ov[k] = (_Float16)o[k];
            *(half2v*)((_Float16*)out + (size_t)node * HC + base) = ov;
        }
    } else {
        if constexpr (PER == 4)
            *(float4*)((float*)out + (size_t)node * HC + base) = *(float4*)o;
        else
            *(float2*)((float*)out + (size_t)node * HC + base) = *(float2*)o;
    }
}

// ---------------------------------------------------------------------------
// per-graph pooling (batch sorted -> contiguous node ranges), no atomics
// ---------------------------------------------------------------------------
__global__ void pool_graph(const float* __restrict__ h, const int* __restrict__ gstart,
                           float* __restrict__ gbuf) {
    int g = blockIdx.x;
    int t = threadIdx.x;                   // 0..127
    int a = gstart[g], b = gstart[g + 1];
    float sum = 0.f, mx = -INFINITY;
    for (int i = a; i < b; ++i) {
        float v = h[(size_t)i * 128 + t];
        sum += v;
        mx = fmaxf(mx, v);
    }
    float cnt = fmaxf((float)(b - a), 1.f);
    gbuf[g * 256 + t]       = sum / cnt;
    gbuf[g * 256 + 128 + t] = (b > a) ? mx : 0.f;
}

// ---------------------------------------------------------------------------
// classifier head: one block (128 threads) per graph
// ---------------------------------------------------------------------------
__global__ void classifier(const float* __restrict__ g,
                           const float* __restrict__ w1, const float* __restrict__ b1,
                           const float* __restrict__ bnp,
                           const float* __restrict__ w2, const float* __restrict__ b2,
                           const float* __restrict__ w3, const float* __restrict__ b3,
                           float* __restrict__ out) {
    __shared__ float sg[256];
    __shared__ float sz1[128];
    __shared__ float sz2[64];
    __shared__ float sz3[2];
    int b = blockIdx.x, t = threadIdx.x;
    sg[t]       = g[b * 256 + t];
    sg[128 + t] = g[b * 256 + 128 + t];
    __syncthreads();
    float acc = b1[t];
    for (int i = 0; i < 256; ++i) acc += sg[i] * w1[i * 128 + t];
    float ga = bnp[t], be = bnp[128 + t], m = bnp[256 + t], va = bnp[384 + t];
    acc = ga * (acc - m) * rsqrtf(va + 1e-5f) + be;
    sz1[t] = fmaxf(acc, 0.f);
    __syncthreads();
    if (t < 64) {
        float a2 = b2[t];
        for (int i = 0; i < 128; ++i) a2 += sz1[i] * w2[i * 64 + t];
        sz2[t] = fmaxf(a2, 0.f);
    }
    __syncthreads();
    if (t < 2) {
        float a3 = b3[t];
        for (int i = 0; i < 64; ++i) a3 += sz2[i] * w3[i * 2 + t];
        sz3[t] = a3;
    }
    __syncthreads();
    if (t < 2) {
        float mm = fmaxf(sz3[0], sz3[1]);
        float lse = mm + logf(expf(sz3[0] - mm) + expf(sz3[1] - mm));
        out[b * 2 + t] = sz3[t] - lse;
    }
}

// ---------------------------------------------------------------------------
// launch
// ---------------------------------------------------------------------------
static inline int cdiv(int a, int b) { return (a + b - 1) / b; }

extern "C" void kernel_launch(void* const* d_in, const int* in_sizes, int n_in,
                              void* d_out, int out_size, void* d_ws, size_t ws_size,
                              hipStream_t stream) {
    const float* x       = (const float*)d_in[0];
    const int*   ei      = (const int*)d_in[1];
    const int*   batch   = (const int*)d_in[2];
    const float* w_in    = (const float*)d_in[3];
    const float* b_in    = (const float*)d_in[4];
    const float* bn_in   = (const float*)d_in[5];
    const float* g1_wl   = (const float*)d_in[6];
    const float* g1_bl   = (const float*)d_in[7];
    const float* g1_wr   = (const float*)d_in[8];
    const float* g1_br   = (const float*)d_in[9];
    const float* g1_att  = (const float*)d_in[10];
    const float* g1_bias = (const float*)d_in[11];
    const float* bn1     = (const float*)d_in[12];
    const float* g2_wl   = (const float*)d_in[13];
    const float* g2_bl   = (const float*)d_in[14];
    const float* g2_wr   = (const float*)d_in[15];
    const float* g2_br   = (const float*)d_in[16];
    const float* g2_att  = (const float*)d_in[17];
    const float* g2_bias = (const float*)d_in[18];
    const float* bn2     = (const float*)d_in[19];
    const float* g3_wl   = (const float*)d_in[20];
    const float* g3_bl   = (const float*)d_in[21];
    const float* g3_wr   = (const float*)d_in[22];
    const float* g3_br   = (const float*)d_in[23];
    const float* g3_att  = (const float*)d_in[24];
    const float* g3_bias = (const float*)d_in[25];
    const float* bn3     = (const float*)d_in[26];
    const float* c_w1    = (const float*)d_in[27];
    const float* c_b1    = (const float*)d_in[28];
    const float* c_bn    = (const float*)d_in[29];
    const float* c_w2    = (const float*)d_in[30];
    const float* c_b2    = (const float*)d_in[31];
    const float* c_w3    = (const float*)d_in[32];
    const float* c_b3    = (const float*)d_in[33];
    float* out = (float*)d_out;

    // ---- workspace layout
    const size_t NHC = (size_t)N_NODES * 256;
    _Float16* a16  = (_Float16*)d_ws;          // GEMM input features [N][K<=256]
    _Float16* xl16 = a16 + NHC;                // GEMM outputs (lin_l)
    _Float16* xr16 = xl16 + NHC;               // GEMM outputs (lin_r)
    _Float16* wt   = xr16 + NHC;               // transposed f16 weights
    _Float16* wt_g1l = wt;                     // [256][64]
    _Float16* wt_g1r = wt + 16384;
    _Float16* wt_g2l = wt + 32768;             // [256][256]
    _Float16* wt_g2r = wt + 98304;
    _Float16* wt_g3l = wt + 163840;            // [128][256]
    _Float16* wt_g3r = wt + 196608;
    float* fbase = (float*)(wt + 262144);      // aligned
    float* bufD = fbase;                       // N*128 f32 (layer-3 gather out)
    float* gbuf = bufD + (size_t)N_NODES * 128;       // 300*256
    int*   iw   = (int*)(gbuf + N_GRAPHS * 256);
    int* deg       = iw;                       // 30000
    int* cnt       = iw + 30000;               // 30000
    int* slocal    = iw + 60000;               // 30000
    int* bsums     = iw + 90000;               // 128
    int* row_start = iw + 90128;               // 30001
    int* esrc      = iw + 120129;              // 270000
    int* gdeg      = iw + 390129;              // 300
    int* glocal    = iw + 390429;              // 300
    int* gbsums    = iw + 390729;              // 8
    int* gstart    = iw + 390737;              // 301

    const int BT = 256;
    const int NT128 = cdiv(N_NODES, 128);      // 235

    // ---- CSR build by destination (same graph for all 3 layers)
    ifill<<<cdiv(60000, BT), BT, 0, stream>>>(deg, 0, 60000);
    ifill<<<cdiv(300, BT), BT, 0, stream>>>(gdeg, 0, 300);
    hist_edges<<<cdiv(E_TOT, BT), BT, 0, stream>>>(ei, deg);
    hist_batch<<<cdiv(N_NODES, BT), BT, 0, stream>>>(batch, gdeg);
    scan_partial<<<cdiv(N_NODES, 256), 256, 0, stream>>>(deg, slocal, bsums, N_NODES);
    scan_tops<<<1, 128, 0, stream>>>(bsums, cdiv(N_NODES, 256));
    scan_add<<<cdiv(N_NODES, BT), BT, 0, stream>>>(slocal, bsums, row_start, N_NODES, E_TOT);
    csr_scatter<<<cdiv(E_TOT, BT), BT, 0, stream>>>(ei, row_start, cnt, esrc);
    scan_partial<<<cdiv(N_GRAPHS, 256), 256, 0, stream>>>(gdeg, glocal, gbsums, N_GRAPHS);
    scan_tops<<<1, 128, 0, stream>>>(gbsums, cdiv(N_GRAPHS, 256));
    scan_add<<<cdiv(N_GRAPHS, BT), BT, 0, stream>>>(glocal, gbsums, gstart, N_GRAPHS, N_NODES);

    // ---- weight prep: transpose + f16 convert (tiny)
    wprep<64, 256><<<cdiv(64 * 256, BT), BT, 0, stream>>>(g1_wl, wt_g1l);
    wprep<64, 256><<<cdiv(64 * 256, BT), BT, 0, stream>>>(g1_wr, wt_g1r);
    wprep<256, 256><<<cdiv(256 * 256, BT), BT, 0, stream>>>(g2_wl, wt_g2l);
    wprep<256, 256><<<cdiv(256 * 256, BT), BT, 0, stream>>>(g2_wr, wt_g2r);
    wprep<256, 128><<<cdiv(256 * 128, BT), BT, 0, stream>>>(g3_wl, wt_g3l);
    wprep<256, 128><<<cdiv(256 * 128, BT), BT, 0, stream>>>(g3_wr, wt_g3r);

    // ---- input layer: h0 = relu(bn(x @ w_in + b_in)) -> a16 [N][64] f16
    node_gemm<5, 64, 4><<<cdiv(N_NODES, 4), 64, 0, stream>>>(x, w_in, b_in, a16, bn_in, N_NODES);

    // ---- GAT layer 1: 64 -> 4x64
    gemm_mfma<64, 256><<<dim3(NT128, 4), 256, 0, stream>>>(
        a16, wt_g1l, g1_bl, wt_g1r, g1_br, xl16, xr16, N_NODES);
    gat_gather<4, 64, _Float16><<<cdiv(N_NODES * 64, BT), BT, 0, stream>>>(
        xl16, xr16, row_start, esrc, g1_att, g1_bias, bn1, a16);

    // ---- GAT layer 2: 256 -> 4x64
    gemm_mfma<256, 256><<<dim3(NT128, 4), 256, 0, stream>>>(
        a16, wt_g2l, g2_bl, wt_g2r, g2_br, xl16, xr16, N_NODES);
    gat_gather<4, 64, _Float16><<<cdiv(N_NODES * 64, BT), BT, 0, stream>>>(
        xl16, xr16, row_start, esrc, g2_att, g2_bias, bn2, a16);

    // ---- GAT layer 3: 256 -> 1x128, gather emits f32 for pooling
    gemm_mfma<256, 128><<<dim3(NT128, 2), 256, 0, stream>>>(
        a16, wt_g3l, g3_bl, wt_g3r, g3_br, xl16, xr16, N_NODES);
    gat_gather<1, 128, float><<<cdiv(N_NODES * 64, BT), BT, 0, stream>>>(
        xl16, xr16, row_start, esrc, g3_att, g3_bias, bn3, bufD);

    // ---- pooling: mean + max per graph -> gbuf (300 x 256)
    pool_graph<<<N_GRAPHS, 128, 0, stream>>>(bufD, gstart, gbuf);

    // ---- classifier head
    classifier<<<N_GRAPHS, 128, 0, stream>>>(gbuf, c_w1, c_b1, c_bn, c_w2, c_b2, c_w3, c_b3, out);
}

// Round 7
// 420.022 us; speedup vs baseline: 8.3969x; 1.0755x over previous
//
#include <hip/hip_runtime.h>
#include <math.h>

#define N_NODES  30000
#define N_EDGES  240000
#define E_TOT    270000   // N_EDGES + N_NODES self loops
#define N_GRAPHS 300

typedef _Float16 half8 __attribute__((ext_vector_type(8)));
typedef _Float16 half4 __attribute__((ext_vector_type(4)));
typedef _Float16 half2v __attribute__((ext_vector_type(2)));
typedef float float4v __attribute__((ext_vector_type(4)));

// ---------------------------------------------------------------------------
// init + histogram (fused)
// ---------------------------------------------------------------------------
__global__ void init_fill(int* __restrict__ deg, int* __restrict__ gdeg) {
    int i = blockIdx.x * blockDim.x + threadIdx.x;
    if (i < 60000) deg[i] = 0;            // deg + cnt (contiguous)
    if (i < 300)   gdeg[i] = 0;
}

__global__ void hist_all(const int* __restrict__ ei, const int* __restrict__ batch,
                         int* __restrict__ deg, int* __restrict__ gdeg) {
    int e = blockIdx.x * blockDim.x + threadIdx.x;
    if (e < E_TOT) {
        int d = (e < N_EDGES) ? ei[N_EDGES + e] : e - N_EDGES;
        atomicAdd(&deg[d], 1);
    }
    if (e < N_NODES) atomicAdd(&gdeg[batch[e]], 1);
}

// ---------------------------------------------------------------------------
// scans
// ---------------------------------------------------------------------------
__global__ void scan_partial(const int* __restrict__ in, int* __restrict__ local,
                             int* __restrict__ bsums, int n) {
    __shared__ int s[256];
    int t = threadIdx.x;
    int gid = blockIdx.x * 256 + t;
    int v = (gid < n) ? in[gid] : 0;
    s[t] = v;
    __syncthreads();
    for (int off = 1; off < 256; off <<= 1) {
        int u = (t >= off) ? s[t - off] : 0;
        __syncthreads();
        s[t] += u;
        __syncthreads();
    }
    if (gid < n) local[gid] = s[t] - v;           // exclusive
    if (t == 255) bsums[blockIdx.x] = s[255];
}

__global__ void scan_tops(int* __restrict__ bsums, int nb) {
    __shared__ int s[128];
    int t = threadIdx.x;
    int v = (t < nb) ? bsums[t] : 0;
    s[t] = v;
    __syncthreads();
    for (int off = 1; off < 128; off <<= 1) {
        int u = (t >= off) ? s[t - off] : 0;
        __syncthreads();
        s[t] += u;
        __syncthreads();
    }
    if (t < nb) bsums[t] = s[t] - v;
}

__global__ void scan_add(const int* __restrict__ local, const int* __restrict__ bsums,
                         int* __restrict__ out, int n, int total) {
    int gid = blockIdx.x * blockDim.x + threadIdx.x;
    if (gid < n) out[gid] = local[gid] + bsums[gid >> 8];
    if (gid == 0) out[n] = total;
}

// one-block exclusive scan for n <= 512 (graph starts)
__global__ void scan_small(const int* __restrict__ in, int* __restrict__ out,
                           int n, int total) {
    __shared__ int s[512];
    int t = threadIdx.x;
    int v = (t < n) ? in[t] : 0;
    s[t] = v;
    __syncthreads();
    for (int off = 1; off < 512; off <<= 1) {
        int u = (t >= off) ? s[t - off] : 0;
        __syncthreads();
        s[t] += u;
        __syncthreads();
    }
    if (t < n) out[t] = s[t] - v;
    if (t == 0) out[n] = total;
}

__global__ void csr_scatter(const int* __restrict__ ei, const int* __restrict__ row_start,
                            int* __restrict__ cnt, int* __restrict__ esrc) {
    int e = blockIdx.x * blockDim.x + threadIdx.x;
    if (e >= E_TOT) return;
    int s, d;
    if (e < N_EDGES) { s = ei[e]; d = ei[N_EDGES + e]; }
    else             { s = e - N_EDGES; d = s; }
    int slot = row_start[d] + atomicAdd(&cnt[d], 1);
    esrc[slot] = s;
}

// ---------------------------------------------------------------------------
// weight prep pair: W[K][COUT] f32 -> Wt[COUT][K] f16; blockIdx.y picks l/r
// ---------------------------------------------------------------------------
template<int K, int COUT>
__global__ void wprep_pair(const float* __restrict__ Wl, const float* __restrict__ Wr,
                           _Float16* __restrict__ Wtl, _Float16* __restrict__ Wtr) {
    const float* W = blockIdx.y ? Wr : Wl;
    _Float16* Wt   = blockIdx.y ? Wtr : Wtl;
    int i = blockIdx.x * blockDim.x + threadIdx.x;
    if (i >= K * COUT) return;
    int k = i / COUT, c = i - k * COUT;
    Wt[(size_t)c * K + k] = (_Float16)W[i];
}

// ---------------------------------------------------------------------------
// MFMA f16 pair GEMM (fp32 accumulate); see Round-5 comments for layouts
// ---------------------------------------------------------------------------
template<int K, int COUT>
__global__ __launch_bounds__(256, 3)
void gemm_mfma(const _Float16* __restrict__ A,
               const _Float16* __restrict__ Wtl, const float* __restrict__ bl,
               const _Float16* __restrict__ Wtr, const float* __restrict__ br,
               _Float16* __restrict__ outl, _Float16* __restrict__ outr, int N) {
    constexpr int BM = 128, BN = 128, BK = 64;
    constexpr int LDK = BK + 8;
    __shared__ _Float16 As[BM][LDK];
    __shared__ _Float16 Bs[BN][LDK];
    const int tid  = threadIdx.x;
    const int wave = tid >> 6;
    const int lane = tid & 63;
    const int l15  = lane & 15;
    const int lq   = lane >> 4;
    const int n0   = blockIdx.x * BM;
    constexpr int CSL = COUT / BN > 0 ? COUT / BN : 1;
    const int sel  = blockIdx.y / CSL;
    const int col0 = (blockIdx.y % CSL) * BN;
    const _Float16* Wt = sel ? Wtr : Wtl;
    const float* bias  = sel ? br : bl;
    _Float16* out      = sel ? outr : outl;

    float4v acc[2][8];
#pragma unroll
    for (int mi = 0; mi < 2; ++mi)
#pragma unroll
        for (int nt = 0; nt < 8; ++nt)
#pragma unroll
            for (int r = 0; r < 4; ++r) acc[mi][nt][r] = 0.f;

    for (int kt = 0; kt < K; kt += BK) {
#pragma unroll
        for (int p = 0; p < 4; ++p) {
            int idx = p * 256 + tid;
            int row = idx >> 3;
            int ch  = (idx & 7) * 8;
            int gn  = n0 + row;
            half8 v = {};
            if (gn < N) v = *(const half8*)(A + (size_t)gn * K + kt + ch);
            *(half8*)(&As[row][ch]) = v;
        }
#pragma unroll
        for (int p = 0; p < 4; ++p) {
            int idx = p * 256 + tid;
            int row = idx >> 3;
            int ch  = (idx & 7) * 8;
            half8 v = *(const half8*)(Wt + (size_t)(col0 + row) * K + kt + ch);
            *(half8*)(&Bs[row][ch]) = v;
        }
        __syncthreads();
#pragma unroll
        for (int kk = 0; kk < BK; kk += 32) {
            half8 af0 = *(const half8*)(&As[wave * 32 + l15][kk + lq * 8]);
            half8 af1 = *(const half8*)(&As[wave * 32 + 16 + l15][kk + lq * 8]);
#pragma unroll
            for (int nt = 0; nt < 8; ++nt) {
                half8 bf = *(const half8*)(&Bs[nt * 16 + l15][kk + lq * 8]);
                acc[0][nt] = __builtin_amdgcn_mfma_f32_16x16x32_f16(af0, bf, acc[0][nt], 0, 0, 0);
                acc[1][nt] = __builtin_amdgcn_mfma_f32_16x16x32_f16(af1, bf, acc[1][nt], 0, 0, 0);
            }
        }
        __syncthreads();
    }
#pragma unroll
    for (int mi = 0; mi < 2; ++mi)
#pragma unroll
        for (int nt = 0; nt < 8; ++nt) {
            int col = col0 + nt * 16 + l15;
            float bv = bias[col];
#pragma unroll
            for (int r = 0; r < 4; ++r) {
                int row = n0 + wave * 32 + mi * 16 + lq * 4 + r;
                if (row < N)
                    out[(size_t)row * COUT + col] = (_Float16)(acc[mi][nt][r] + bv);
            }
        }
}

// ---------------------------------------------------------------------------
// input layer GEMM (tiny K=5): f32 math, bn+relu, emits f16 [N][64]
// ---------------------------------------------------------------------------
template<int CIN, int COUT, int NT>
__global__ void node_gemm(const float* __restrict__ h, const float* __restrict__ W,
                          const float* __restrict__ bias, _Float16* __restrict__ out,
                          const float* __restrict__ bnp, int n_nodes) {
    __shared__ float sh[NT][CIN];
    const int n0 = blockIdx.x * NT;
    const int t  = threadIdx.x;
    for (int i = t; i < NT * CIN; i += COUT) {
        int nn = i / CIN, ci = i - nn * CIN;
        int n = n0 + nn;
        sh[nn][ci] = (n < n_nodes) ? h[(size_t)n * CIN + ci] : 0.f;
    }
    __syncthreads();
    float acc[NT];
#pragma unroll
    for (int j = 0; j < NT; ++j) acc[j] = bias[t];
    for (int ci = 0; ci < CIN; ++ci) {
        float w = W[ci * COUT + t];
#pragma unroll
        for (int j = 0; j < NT; ++j) acc[j] += sh[j][ci] * w;
    }
#pragma unroll
    for (int j = 0; j < NT; ++j) {
        int n = n0 + j;
        if (n >= n_nodes) break;
        float v = acc[j];
        float g = bnp[t], be = bnp[COUT + t], m = bnp[2 * COUT + t], va = bnp[3 * COUT + t];
        v = g * (v - m) * rsqrtf(va + 1e-5f) + be;
        v = fmaxf(v, 0.f);
        out[(size_t)n * COUT + t] = (_Float16)v;
    }
}

// ---------------------------------------------------------------------------
// fused GATv2 gather, 4-edge unrolled online softmax.
// One wave per node, all H heads. The 4-edge batch turns the per-edge serial
// chain (scattered load -> 4-6 hop shuffle reduce -> 2 exp) into one chain
// per 4 edges with 4-way ILP/MLP inside.
// ---------------------------------------------------------------------------
template<int H, int C, typename TOUT>
__global__ __launch_bounds__(256)
void gat_gather(const _Float16* __restrict__ xl, const _Float16* __restrict__ xr,
                const int* __restrict__ row_start, const int* __restrict__ esrc,
                const float* __restrict__ att, const float* __restrict__ gbias,
                const float* __restrict__ bnp, TOUT* __restrict__ out) {
    constexpr int HC    = H * C;
    constexpr int PER   = HC / 64;         // channels per lane (4 or 2)
    constexpr int GROUP = 64 / H;          // lanes per head (16 or 64)
    int node = (blockIdx.x * blockDim.x + threadIdx.x) >> 6;
    int lane = threadIdx.x & 63;
    if (node >= N_NODES) return;
    const int base = lane * PER;

    float rr[PER], av[PER], acc[PER];
    if constexpr (PER == 4) {
        half4 rv = *(const half4*)(xr + (size_t)node * HC + base);
#pragma unroll
        for (int k = 0; k < PER; ++k) rr[k] = (float)rv[k];
        *(float4*)av = *(const float4*)(att + base);
    } else {
        half2v rv = *(const half2v*)(xr + (size_t)node * HC + base);
#pragma unroll
        for (int k = 0; k < PER; ++k) rr[k] = (float)rv[k];
        *(float2*)av = *(const float2*)(att + base);
    }
#pragma unroll
    for (int k = 0; k < PER; ++k) acc[k] = 0.f;

    float m = -INFINITY, l = 0.f;
    const int j0 = row_start[node], j1 = row_start[node + 1];
    for (int jc = j0; jc < j1; jc += 64) {
        int nedge = min(64, j1 - jc);
        int ev = (jc + lane < j1) ? esrc[jc + lane] : 0;   // coalesced prefetch
        int jj = 0;
        // ---- 4-edge batches
        for (; jj + 4 <= nedge; jj += 4) {
            int s[4];
#pragma unroll
            for (int u = 0; u < 4; ++u) s[u] = __shfl(ev, jj + u, 64);
            float xs[4][PER];
#pragma unroll
            for (int u = 0; u < 4; ++u) {
                if constexpr (PER == 4) {
                    half4 xv = *(const half4*)(xl + (size_t)s[u] * HC + base);
#pragma unroll
                    for (int k = 0; k < PER; ++k) xs[u][k] = (float)xv[k];
                } else {
                    half2v xv = *(const half2v*)(xl + (size_t)s[u] * HC + base);
#pragma unroll
                    for (int k = 0; k < PER; ++k) xs[u][k] = (float)xv[k];
                }
            }
            float p[4];
#pragma unroll
            for (int u = 0; u < 4; ++u) {
                float pp = 0.f;
#pragma unroll
                for (int k = 0; k < PER; ++k) {
                    float v = xs[u][k] + rr[k];
                    v = (v > 0.f) ? v : 0.2f * v;          // leaky_relu 0.2
                    pp = fmaf(v, av[k], pp);
                }
                p[u] = pp;
            }
            // interleaved reductions: hop latencies overlap across 4 edges
#pragma unroll
            for (int off = GROUP / 2; off; off >>= 1) {
#pragma unroll
                for (int u = 0; u < 4; ++u) p[u] += __shfl_xor(p[u], off, 64);
            }
            float mx = fmaxf(fmaxf(p[0], p[1]), fmaxf(p[2], p[3]));
            float mn = fmaxf(m, mx);
            float scale = __expf(m - mn);                  // first batch: exp(-inf)=0
            float w[4];
#pragma unroll
            for (int u = 0; u < 4; ++u) w[u] = __expf(p[u] - mn);
            l = fmaf(l, scale, (w[0] + w[1]) + (w[2] + w[3]));
#pragma unroll
            for (int k = 0; k < PER; ++k) {
                float t = fmaf(w[0], xs[0][k],
                          fmaf(w[1], xs[1][k],
                          fmaf(w[2], xs[2][k], w[3] * xs[3][k])));
                acc[k] = fmaf(acc[k], scale, t);
            }
            m = mn;
        }
        // ---- tail edges
        for (; jj < nedge; ++jj) {
            int s = __shfl(ev, jj, 64);
            float xls[PER];
            if constexpr (PER == 4) {
                half4 xv = *(const half4*)(xl + (size_t)s * HC + base);
#pragma unroll
                for (int k = 0; k < PER; ++k) xls[k] = (float)xv[k];
            } else {
                half2v xv = *(const half2v*)(xl + (size_t)s * HC + base);
#pragma unroll
                for (int k = 0; k < PER; ++k) xls[k] = (float)xv[k];
            }
            float p = 0.f;
#pragma unroll
            for (int k = 0; k < PER; ++k) {
                float v = xls[k] + rr[k];
                v = (v > 0.f) ? v : 0.2f * v;
                p = fmaf(v, av[k], p);
            }
#pragma unroll
            for (int off = GROUP / 2; off; off >>= 1) p += __shfl_xor(p, off, 64);
            float mn    = fmaxf(m, p);
            float scale = __expf(m - mn);
            float w     = __expf(p - mn);
            l = fmaf(l, scale, w);
#pragma unroll
            for (int k = 0; k < PER; ++k) acc[k] = fmaf(acc[k], scale, w * xls[k]);
            m = mn;
        }
    }
    float inv = 1.f / (l + 1e-16f);
    float o[PER];
#pragma unroll
    for (int k = 0; k < PER; ++k) {
        float v = fmaf(acc[k], inv, gbias[base + k]);
        float g  = bnp[base + k], be = bnp[HC + base + k];
        float mm = bnp[2 * HC + base + k], va = bnp[3 * HC + base + k];
        v = g * (v - mm) * rsqrtf(va + 1e-5f) + be;
        o[k] = (v > 0.f) ? v : (__expf(v) - 1.f);          // elu
    }
    if constexpr (sizeof(TOUT) == 2) {
        if constexpr (PER == 4) {
            half4 ov;
#pragma unroll
            for (int k = 0; k < PER; ++k) ov[k] = (_Float16)o[k];
            *(half4*)((_Float16*)out + (size_t)node * HC + base) = ov;
        } else {
            half2v ov;
#pragma unroll
            for (int k = 0; k < PER; ++k) ov[k] = (_Float16)o[k];
            *(half2v*)((_Float16*)out + (size_t)node * HC + base) = ov;
        }
    } else {
        if constexpr (PER == 4)
            *(float4*)((float*)out + (size_t)node * HC + base) = *(float4*)o;
        else
            *(float2*)((float*)out + (size_t)node * HC + base) = *(float2*)o;
    }
}

// ---------------------------------------------------------------------------
// per-graph pooling (batch sorted -> contiguous node ranges), no atomics
// ---------------------------------------------------------------------------
__global__ void pool_graph(const float* __restrict__ h, const int* __restrict__ gstart,
                           float* __restrict__ gbuf) {
    int g = blockIdx.x;
    int t = threadIdx.x;                   // 0..127
    int a = gstart[g], b = gstart[g + 1];
    float sum = 0.f, mx = -INFINITY;
    for (int i = a; i < b; ++i) {
        float v = h[(size_t)i * 128 + t];
        sum += v;
        mx = fmaxf(mx, v);
    }
    float cnt = fmaxf((float)(b - a), 1.f);
    gbuf[g * 256 + t]       = sum / cnt;
    gbuf[g * 256 + 128 + t] = (b > a) ? mx : 0.f;
}

// ---------------------------------------------------------------------------
// classifier head: one block (128 threads) per graph
// ---------------------------------------------------------------------------
__global__ void classifier(const float* __restrict__ g,
                           const float* __restrict__ w1, const float* __restrict__ b1,
                           const float* __restrict__ bnp,
                           const float* __restrict__ w2, const float* __restrict__ b2,
                           const float* __restrict__ w3, const float* __restrict__ b3,
                           float* __restrict__ out) {
    __shared__ float sg[256];
    __shared__ float sz1[128];
    __shared__ float sz2[64];
    __shared__ float sz3[2];
    int b = blockIdx.x, t = threadIdx.x;
    sg[t]       = g[b * 256 + t];
    sg[128 + t] = g[b * 256 + 128 + t];
    __syncthreads();
    float acc = b1[t];
    for (int i = 0; i < 256; ++i) acc += sg[i] * w1[i * 128 + t];
    float ga = bnp[t], be = bnp[128 + t], m = bnp[256 + t], va = bnp[384 + t];
    acc = ga * (acc - m) * rsqrtf(va + 1e-5f) + be;
    sz1[t] = fmaxf(acc, 0.f);
    __syncthreads();
    if (t < 64) {
        float a2 = b2[t];
        for (int i = 0; i < 128; ++i) a2 += sz1[i] * w2[i * 64 + t];
        sz2[t] = fmaxf(a2, 0.f);
    }
    __syncthreads();
    if (t < 2) {
        float a3 = b3[t];
        for (int i = 0; i < 64; ++i) a3 += sz2[i] * w3[i * 2 + t];
        sz3[t] = a3;
    }
    __syncthreads();
    if (t < 2) {
        float mm = fmaxf(sz3[0], sz3[1]);
        float lse = mm + logf(expf(sz3[0] - mm) + expf(sz3[1] - mm));
        out[b * 2 + t] = sz3[t] - lse;
    }
}

// ---------------------------------------------------------------------------
// launch
// ---------------------------------------------------------------------------
static inline int cdiv(int a, int b) { return (a + b - 1) / b; }

extern "C" void kernel_launch(void* const* d_in, const int* in_sizes, int n_in,
                              void* d_out, int out_size, void* d_ws, size_t ws_size,
                              hipStream_t stream) {
    const float* x       = (const float*)d_in[0];
    const int*   ei      = (const int*)d_in[1];
    const int*   batch   = (const int*)d_in[2];
    const float* w_in    = (const float*)d_in[3];
    const float* b_in    = (const float*)d_in[4];
    const float* bn_in   = (const float*)d_in[5];
    const float* g1_wl   = (const float*)d_in[6];
    const float* g1_bl   = (const float*)d_in[7];
    const float* g1_wr   = (const float*)d_in[8];
    const float* g1_br   = (const float*)d_in[9];
    const float* g1_att  = (const float*)d_in[10];
    const float* g1_bias = (const float*)d_in[11];
    const float* bn1     = (const float*)d_in[12];
    const float* g2_wl   = (const float*)d_in[13];
    const float* g2_bl   = (const float*)d_in[14];
    const float* g2_wr   = (const float*)d_in[15];
    const float* g2_br   = (const float*)d_in[16];
    const float* g2_att  = (const float*)d_in[17];
    const float* g2_bias = (const float*)d_in[18];
    const float* bn2     = (const float*)d_in[19];
    const float* g3_wl   = (const float*)d_in[20];
    const float* g3_bl   = (const float*)d_in[21];
    const float* g3_wr   = (const float*)d_in[22];
    const float* g3_br   = (const float*)d_in[23];
    const float* g3_att  = (const float*)d_in[24];
    const float* g3_bias = (const float*)d_in[25];
    const float* bn3     = (const float*)d_in[26];
    const float* c_w1    = (const float*)d_in[27];
    const float* c_b1    = (const float*)d_in[28];
    const float* c_bn    = (const float*)d_in[29];
    const float* c_w2    = (const float*)d_in[30];
    const float* c_b2    = (const float*)d_in[31];
    const float* c_w3    = (const float*)d_in[32];
    const float* c_b3    = (const float*)d_in[33];
    float* out = (float*)d_out;

    // ---- workspace layout
    const size_t NHC = (size_t)N_NODES * 256;
    _Float16* a16  = (_Float16*)d_ws;          // GEMM input features [N][K<=256]
    _Float16* xl16 = a16 + NHC;                // GEMM outputs (lin_l)
    _Float16* xr16 = xl16 + NHC;               // GEMM outputs (lin_r)
    _Float16* wt   = xr16 + NHC;               // transposed f16 weights
    _Float16* wt_g1l = wt;                     // [256][64]
    _Float16* wt_g1r = wt + 16384;
    _Float16* wt_g2l = wt + 32768;             // [256][256]
    _Float16* wt_g2r = wt + 98304;
    _Float16* wt_g3l = wt + 163840;            // [128][256]
    _Float16* wt_g3r = wt + 196608;
    float* fbase = (float*)(wt + 262144);      // aligned
    float* bufD = fbase;                       // N*128 f32 (layer-3 gather out)
    float* gbuf = bufD + (size_t)N_NODES * 128;       // 300*256
    int*   iw   = (int*)(gbuf + N_GRAPHS * 256);
    int* deg       = iw;                       // 30000
    int* cnt       = iw + 30000;               // 30000
    int* slocal    = iw + 60000;               // 30000
    int* bsums     = iw + 90000;               // 128
    int* row_start = iw + 90128;               // 30001
    int* esrc      = iw + 120129;              // 270000
    int* gdeg      = iw + 390129;              // 300
    int* gstart    = iw + 390429;              // 301

    const int BT = 256;
    const int NT128 = cdiv(N_NODES, 128);      // 235

    // ---- CSR build by destination (same graph for all 3 layers)
    init_fill<<<cdiv(60000, BT), BT, 0, stream>>>(deg, gdeg);
    hist_all<<<cdiv(E_TOT, BT), BT, 0, stream>>>(ei, batch, deg, gdeg);
    scan_partial<<<cdiv(N_NODES, 256), 256, 0, stream>>>(deg, slocal, bsums, N_NODES);
    scan_tops<<<1, 128, 0, stream>>>(bsums, cdiv(N_NODES, 256));
    scan_add<<<cdiv(N_NODES, BT), BT, 0, stream>>>(slocal, bsums, row_start, N_NODES, E_TOT);
    csr_scatter<<<cdiv(E_TOT, BT), BT, 0, stream>>>(ei, row_start, cnt, esrc);
    scan_small<<<1, 512, 0, stream>>>(gdeg, gstart, N_GRAPHS, N_NODES);

    // ---- weight prep: transpose + f16 convert (3 fused pair launches)
    wprep_pair<64, 256><<<dim3(cdiv(64 * 256, BT), 2), BT, 0, stream>>>(g1_wl, g1_wr, wt_g1l, wt_g1r);
    wprep_pair<256, 256><<<dim3(cdiv(256 * 256, BT), 2), BT, 0, stream>>>(g2_wl, g2_wr, wt_g2l, wt_g2r);
    wprep_pair<256, 128><<<dim3(cdiv(256 * 128, BT), 2), BT, 0, stream>>>(g3_wl, g3_wr, wt_g3l, wt_g3r);

    // ---- input layer: h0 = relu(bn(x @ w_in + b_in)) -> a16 [N][64] f16
    node_gemm<5, 64, 4><<<cdiv(N_NODES, 4), 64, 0, stream>>>(x, w_in, b_in, a16, bn_in, N_NODES);

    // ---- GAT layer 1: 64 -> 4x64
    gemm_mfma<64, 256><<<dim3(NT128, 4), 256, 0, stream>>>(
        a16, wt_g1l, g1_bl, wt_g1r, g1_br, xl16, xr16, N_NODES);
    gat_gather<4, 64, _Float16><<<cdiv(N_NODES * 64, BT), BT, 0, stream>>>(
        xl16, xr16, row_start, esrc, g1_att, g1_bias, bn1, a16);

    // ---- GAT layer 2: 256 -> 4x64
    gemm_mfma<256, 256><<<dim3(NT128, 4), 256, 0, stream>>>(
        a16, wt_g2l, g2_bl, wt_g2r, g2_br, xl16, xr16, N_NODES);
    gat_gather<4, 64, _Float16><<<cdiv(N_NODES * 64, BT), BT, 0, stream>>>(
        xl16, xr16, row_start, esrc, g2_att, g2_bias, bn2, a16);

    // ---- GAT layer 3: 256 -> 1x128, gather emits f32 for pooling
    gemm_mfma<256, 128><<<dim3(NT128, 2), 256, 0, stream>>>(
        a16, wt_g3l, g3_bl, wt_g3r, g3_br, xl16, xr16, N_NODES);
    gat_gather<1, 128, float><<<cdiv(N_NODES * 64, BT), BT, 0, stream>>>(
        xl16, xr16, row_start, esrc, g3_att, g3_bias, bn3, bufD);

    // ---- pooling: mean + max per graph -> gbuf (300 x 256)
    pool_graph<<<N_GRAPHS, 128, 0, stream>>>(bufD, gstart, gbuf);

    // ---- classifier head
    classifier<<<N_GRAPHS, 128, 0, stream>>>(gbuf, c_w1, c_b1, c_bn, c_w2, c_b2, c_w3, c_b3, out);
}